// Round 2
// baseline (1306.081 us; speedup 1.0000x reference)
//
#include <hip/hip_runtime.h>
#include <hip/hip_bf16.h>

typedef __bf16 bf16_t;
typedef __bf16 bf16x4 __attribute__((ext_vector_type(4)));
typedef __bf16 bf16x8 __attribute__((ext_vector_type(8)));
typedef float f32x4 __attribute__((ext_vector_type(4)));

#define BB 2
#define SS 4096
#define DD 1024
#define VV 32000
#define HH 8
#define CC 256
#define NC 16
#define QKVW 1280   // q(128) | k(128) | v(1024)

#define GLD_LDS16(gp, lp) __builtin_amdgcn_global_load_lds( \
    (const __attribute__((address_space(1))) void*)(gp),    \
    (__attribute__((address_space(3))) void*)(lp), 16, 0, 0)

// ---------------- ctx: emb gather + 4-tap causal sum ----------------
__global__ __launch_bounds__(256) void ctx_kernel(
    const int* __restrict__ x, const float* __restrict__ emb,
    float* __restrict__ ctx, bf16_t* __restrict__ ctxb)
{
  const int row = blockIdx.x;            // b*SS + s
  const int b = row >> 12, s = row & (SS - 1);
  const int t = threadIdx.x;             // d = t*4
  float4 a = make_float4(0.f, 0.f, 0.f, 0.f);
  #pragma unroll
  for (int o = 0; o < 4; ++o) {
    if (s - o >= 0) {
      const int idx = x[b * SS + s - o];
      const float4 e = *(const float4*)(emb + (size_t)idx * DD + t * 4);
      a.x += e.x; a.y += e.y; a.z += e.z; a.w += e.w;
    }
  }
  *(float4*)(ctx + (size_t)row * DD + t * 4) = a;
  bf16x4 bv;
  bv[0] = (__bf16)a.x; bv[1] = (__bf16)a.y; bv[2] = (__bf16)a.z; bv[3] = (__bf16)a.w;
  *(bf16x4*)(ctxb + (size_t)row * DD + t * 4) = bv;
}

// ---------------- transpose + f32->bf16: dst[c][r] = src[r][c] ----------------
__global__ __launch_bounds__(256) void transpose_cvt(
    const float* __restrict__ src, bf16_t* __restrict__ dst,
    int srcRows, int srcCols)
{
  __shared__ __align__(16) float tile[64][65];
  const int c0 = blockIdx.x * 64, r0 = blockIdx.y * 64;
  const int tc = threadIdx.x & 63, tq = threadIdx.x >> 6;
  #pragma unroll
  for (int k = 0; k < 16; ++k) {
    const int r = k * 4 + tq;
    tile[r][tc] = src[(size_t)(r0 + r) * srcCols + c0 + tc];
  }
  __syncthreads();
  #pragma unroll
  for (int k = 0; k < 16; ++k) {
    const int cO = k * 4 + tq;
    dst[(size_t)(c0 + cO) * srcRows + r0 + tc] = (__bf16)tile[tc][cO];
  }
}

// ---------------- m97-style bf16 MFMA GEMM: C[M,N] = A[M,K] @ BT[N,K]^T ----------------
// EPI: 0=none, 1=+bias[col], 2=+res[row*N+col]
template<int EPI>
__global__ __launch_bounds__(256) void gemm_bf16_kernel(
    const bf16_t* __restrict__ A, const bf16_t* __restrict__ BT,
    float* __restrict__ C, const float* __restrict__ extra,
    int N, int K)
{
  __shared__ __align__(16) bf16_t As[128 * 32];
  __shared__ __align__(16) bf16_t Bs[128 * 32];
  const int n0 = blockIdx.x * 128;
  const int m0 = blockIdx.y * 128;
  const int t = threadIdx.x;
  const int w = t >> 6, lane = t & 63;
  const int wm = (w >> 1) * 64, wn = (w & 1) * 64;
  const int lr = lane & 15, lk = (lane >> 4) * 8;
  f32x4 acc[4][4] = {};

  for (int k0 = 0; k0 < K; k0 += 32) {
    #pragma unroll
    for (int j = 0; j < 2; ++j) {
      const int e = (j * 256 + t) * 8;          // element in 128x32 tile (row*32+col)
      const bf16_t* ga = A  + (size_t)(m0 + (e >> 5)) * K + k0 + (e & 31);
      GLD_LDS16(ga, As + j * 2048 + w * 512);
      const bf16_t* gb = BT + (size_t)(n0 + (e >> 5)) * K + k0 + (e & 31);
      GLD_LDS16(gb, Bs + j * 2048 + w * 512);
    }
    asm volatile("s_waitcnt vmcnt(0)" ::: "memory");
    __syncthreads();
    bf16x8 af[4], bfr[4];
    #pragma unroll
    for (int i = 0; i < 4; ++i) {
      af[i]  = *(const bf16x8*)(As + (wm + i * 16 + lr) * 32 + lk);
      bfr[i] = *(const bf16x8*)(Bs + (wn + i * 16 + lr) * 32 + lk);
    }
    #pragma unroll
    for (int mi = 0; mi < 4; ++mi)
      #pragma unroll
      for (int ni = 0; ni < 4; ++ni)
        acc[mi][ni] = __builtin_amdgcn_mfma_f32_16x16x32_bf16(af[mi], bfr[ni], acc[mi][ni], 0, 0, 0);
    __syncthreads();
  }
  // C/D layout: col = lane&15, row = (lane>>4)*4 + reg   [m89-verified]
  #pragma unroll
  for (int mi = 0; mi < 4; ++mi) {
    #pragma unroll
    for (int r = 0; r < 4; ++r) {
      const int row = m0 + wm + mi * 16 + (lane >> 4) * 4 + r;
      #pragma unroll
      for (int ni = 0; ni < 4; ++ni) {
        const int col = n0 + wn + ni * 16 + (lane & 15);
        float v = acc[mi][ni][r];
        if (EPI == 1) v += extra[col];
        if (EPI == 2) v += extra[(size_t)row * N + col];
        C[(size_t)row * N + col] = v;
      }
    }
  }
}

// ---------------- phi on q|k region (cols 0..255 of qkv) ----------------
__global__ __launch_bounds__(256) void phi_kernel(float* __restrict__ qkv)
{
  const int id = blockIdx.x * 256 + threadIdx.x;   // 8192*256
  const int row = id >> 8, cix = id & 255;
  const size_t off = (size_t)row * QKVW + cix;
  const float v = qkv[off];
  qkv[off] = v > 0.f ? v + 1.f : __expf(v);
}

// ---------------- per-chunk G = K^T V and ksum ----------------
__global__ __launch_bounds__(256) void gstate_kernel(
    const float* __restrict__ qkv, float* __restrict__ G, float* __restrict__ KS)
{
  const int g = blockIdx.x;                    // b*128 + c*8 + h
  const int h = g & 7, c = (g >> 3) & 15, b = g >> 7;
  const int t = threadIdx.x;
  const int i = t >> 4, dg = t & 15;           // k-index, 8-col group
  const int srcbase = b * SS + c * CC;
  __shared__ __align__(16) float k_lds[64][16];
  __shared__ __align__(16) float v_lds[64][128];
  float acc[8] = {0,0,0,0,0,0,0,0};
  float ks = 0.f;
  for (int st = 0; st < 4; ++st) {
    __syncthreads();
    { const int sl = t >> 2, i0 = (t & 3) * 4;
      *(float4*)&k_lds[sl][i0] =
        *(const float4*)(qkv + (size_t)(srcbase + st * 64 + sl) * QKVW + 128 + h * 16 + i0); }
    #pragma unroll
    for (int vv = 0; vv < 8; ++vv) {
      const int sl = (t >> 5) + vv * 8, col = (t & 31) * 4;
      *(float4*)&v_lds[sl][col] =
        *(const float4*)(qkv + (size_t)(srcbase + st * 64 + sl) * QKVW + 256 + h * 128 + col);
    }
    __syncthreads();
    for (int sl = 0; sl < 64; ++sl) {
      const float kv = k_lds[sl][i];
      if (dg == 0) ks += kv;
      const float4 va = *(const float4*)&v_lds[sl][dg * 8];
      const float4 vb = *(const float4*)&v_lds[sl][dg * 8 + 4];
      acc[0] = fmaf(kv, va.x, acc[0]); acc[1] = fmaf(kv, va.y, acc[1]);
      acc[2] = fmaf(kv, va.z, acc[2]); acc[3] = fmaf(kv, va.w, acc[3]);
      acc[4] = fmaf(kv, vb.x, acc[4]); acc[5] = fmaf(kv, vb.y, acc[5]);
      acc[6] = fmaf(kv, vb.z, acc[6]); acc[7] = fmaf(kv, vb.w, acc[7]);
    }
  }
  float* gp = G + ((size_t)(b * NC + c) * HH + h) * 2048 + i * 128 + dg * 8;
  *(float4*)gp       = make_float4(acc[0], acc[1], acc[2], acc[3]);
  *(float4*)(gp + 4) = make_float4(acc[4], acc[5], acc[6], acc[7]);
  if (dg == 0) KS[((size_t)(b * NC + c) * HH + h) * 16 + i] = ks;
}

// ---------------- attention: intra (masked) + bypass (prev chunk) + state ----------------
__global__ __launch_bounds__(256) void attn_kernel(
    const float* __restrict__ qkv, const float* __restrict__ Gb,
    const float* __restrict__ KS, bf16_t* __restrict__ outp)
{
  const int bid = blockIdx.x;                   // 512 = b*256 + c*16 + h*2 + dh
  const int dh = bid & 1, h = (bid >> 1) & 7, c = (bid >> 4) & 15, b = bid >> 8;
  const int t = threadIdx.x;
  const int cg = t & 3, rg = t >> 2;            // 16-col group, 4-row group
  const int rowbase = b * SS + c * CC;

  __shared__ __align__(16) float k_lds[64][16];
  __shared__ __align__(16) float v_lds[64][64];
  __shared__ __align__(16) float s_lds[16 * 64];
  __shared__ float z_lds[16];

  float q[4][16];
  #pragma unroll
  for (int rr = 0; rr < 4; ++rr) {
    const float* qp = qkv + (size_t)(rowbase + rg * 4 + rr) * QKVW + h * 16;
    #pragma unroll
    for (int i4 = 0; i4 < 4; ++i4) {
      const float4 qv = *(const float4*)(qp + i4 * 4);
      q[rr][i4*4+0] = qv.x; q[rr][i4*4+1] = qv.y; q[rr][i4*4+2] = qv.z; q[rr][i4*4+3] = qv.w;
    }
  }
  float acc[4][16] = {};
  float den[4] = {0.f, 0.f, 0.f, 0.f};

  for (int ph = 0; ph < 2; ++ph) {
    const int cc = c - ph;                       // ph0: current chunk (masked); ph1: prev chunk
    if (cc < 0) break;
    const int srcbase = b * SS + cc * CC;
    const bool masked = (ph == 0);
    for (int st = 0; st < 4; ++st) {
      __syncthreads();
      { const int sl = t >> 2, i0 = (t & 3) * 4;
        *(float4*)&k_lds[sl][i0] =
          *(const float4*)(qkv + (size_t)(srcbase + st * 64 + sl) * QKVW + 128 + h * 16 + i0); }
      #pragma unroll
      for (int vv = 0; vv < 4; ++vv) {
        const int sl = (t >> 4) + vv * 16, col = (t & 15) * 4;
        *(float4*)&v_lds[sl][col] =
          *(const float4*)(qkv + (size_t)(srcbase + st * 64 + sl) * QKVW + 256 + h * 128 + dh * 64 + col);
      }
      __syncthreads();
      for (int sl = 0; sl < 64; ++sl) {
        float kv[16], vvv[16];
        #pragma unroll
        for (int i4 = 0; i4 < 4; ++i4) {
          const float4 kf = *(const float4*)&k_lds[sl][i4 * 4];
          kv[i4*4+0] = kf.x; kv[i4*4+1] = kf.y; kv[i4*4+2] = kf.z; kv[i4*4+3] = kf.w;
          const float4 vf = *(const float4*)&v_lds[sl][cg * 16 + i4 * 4];
          vvv[i4*4+0] = vf.x; vvv[i4*4+1] = vf.y; vvv[i4*4+2] = vf.z; vvv[i4*4+3] = vf.w;
        }
        const int sidx = st * 64 + sl;
        #pragma unroll
        for (int rr = 0; rr < 4; ++rr) {
          float a = 0.f;
          #pragma unroll
          for (int i = 0; i < 16; ++i) a = fmaf(q[rr][i], kv[i], a);
          if (masked && sidx > rg * 4 + rr) a = 0.f;
          den[rr] += a;                          // intra: q.kcum ; bypass: q.bksum
          #pragma unroll
          for (int e = 0; e < 16; ++e) acc[rr][e] = fmaf(a, vvv[e], acc[rr][e]);
        }
      }
    }
  }

  if (c >= 2) {                                  // long-range state: sum_{j<=c-2} G_j
    float sa0 = 0.f, sa1 = 0.f, sa2 = 0.f, sa3 = 0.f;
    const int si = t >> 4, sc = (t & 15) * 4;
    for (int j = 0; j + 2 <= c; ++j) {
      const float4 gv = *(const float4*)(Gb + ((size_t)(b * NC + j) * HH + h) * 2048
                                            + si * 128 + dh * 64 + sc);
      sa0 += gv.x; sa1 += gv.y; sa2 += gv.z; sa3 += gv.w;
    }
    if (t < 16) {
      float z = 0.f;
      for (int j = 0; j + 2 <= c; ++j) z += KS[((size_t)(b * NC + j) * HH + h) * 16 + t];
      z_lds[t] = z;
    }
    *(float4*)&s_lds[si * 64 + sc] = make_float4(sa0, sa1, sa2, sa3);
    __syncthreads();
    #pragma unroll
    for (int i = 0; i < 16; ++i) {
      float sv[16];
      #pragma unroll
      for (int e4 = 0; e4 < 4; ++e4) {
        const float4 f = *(const float4*)&s_lds[i * 64 + cg * 16 + e4 * 4];
        sv[e4*4+0] = f.x; sv[e4*4+1] = f.y; sv[e4*4+2] = f.z; sv[e4*4+3] = f.w;
      }
      const float zi = z_lds[i];
      #pragma unroll
      for (int rr = 0; rr < 4; ++rr) {
        const float qv = q[rr][i];
        den[rr] = fmaf(qv, zi, den[rr]);
        #pragma unroll
        for (int e = 0; e < 16; ++e) acc[rr][e] = fmaf(qv, sv[e], acc[rr][e]);
      }
    }
  }

  const size_t obase = (size_t)rowbase * DD + h * 128 + dh * 64 + cg * 16;
  #pragma unroll
  for (int rr = 0; rr < 4; ++rr) {
    const float inv = 1.0f / (den[rr] + 1e-6f);
    bf16_t* op = outp + obase + (size_t)(rg * 4 + rr) * DD;
    #pragma unroll
    for (int e4 = 0; e4 < 4; ++e4) {
      bf16x4 bv;
      bv[0] = (__bf16)(acc[rr][e4*4+0] * inv); bv[1] = (__bf16)(acc[rr][e4*4+1] * inv);
      bv[2] = (__bf16)(acc[rr][e4*4+2] * inv); bv[3] = (__bf16)(acc[rr][e4*4+3] * inv);
      *(bf16x4*)(op + e4 * 4) = bv;
    }
  }
}

// ---------------- LayerNorm (eps 1e-5) -> bf16 ----------------
__global__ __launch_bounds__(256) void ln_kernel(
    const float* __restrict__ hbuf, const float* __restrict__ g,
    const float* __restrict__ bta, bf16_t* __restrict__ out)
{
  const int row = blockIdx.x;
  const int t = threadIdx.x;
  const float4 x = ((const float4*)(hbuf + (size_t)row * DD))[t];
  float s  = x.x + x.y + x.z + x.w;
  float s2 = x.x*x.x + x.y*x.y + x.z*x.z + x.w*x.w;
  #pragma unroll
  for (int off = 32; off > 0; off >>= 1) {
    s  += __shfl_down(s,  off, 64);
    s2 += __shfl_down(s2, off, 64);
  }
  __shared__ float ws[8];
  if ((t & 63) == 0) { ws[(t >> 6) * 2] = s; ws[(t >> 6) * 2 + 1] = s2; }
  __syncthreads();
  const float ts  = ws[0] + ws[2] + ws[4] + ws[6];
  const float ts2 = ws[1] + ws[3] + ws[5] + ws[7];
  const float mu  = ts * (1.0f / DD);
  const float var = ts2 * (1.0f / DD) - mu * mu;
  const float inv = rsqrtf(var + 1e-5f);
  const float4 gv = ((const float4*)g)[t];
  const float4 bv = ((const float4*)bta)[t];
  bf16x4 o;
  o[0] = (__bf16)((x.x - mu) * inv * gv.x + bv.x);
  o[1] = (__bf16)((x.y - mu) * inv * gv.y + bv.y);
  o[2] = (__bf16)((x.z - mu) * inv * gv.z + bv.z);
  o[3] = (__bf16)((x.w - mu) * inv * gv.w + bv.w);
  *(bf16x4*)(out + (size_t)row * DD + t * 4) = o;
}

extern "C" void kernel_launch(void* const* d_in, const int* in_sizes, int n_in,
                              void* d_out, int out_size, void* d_ws, size_t ws_size,
                              hipStream_t stream) {
  (void)in_sizes; (void)n_in; (void)out_size; (void)ws_size;
  const int*   x    = (const int*)d_in[0];
  const float* emb  = (const float*)d_in[1];
  const float* Wq   = (const float*)d_in[2];
  const float* Wk   = (const float*)d_in[3];
  const float* Wv   = (const float*)d_in[4];
  const float* Wo   = (const float*)d_in[5];
  const float* ln_g = (const float*)d_in[6];
  const float* ln_b = (const float*)d_in[7];
  const float* outW = (const float*)d_in[8];
  const float* outb = (const float*)d_in[9];
  float* out = (float*)d_out;

  char* ws = (char*)d_ws;
  float*  ctx_f32 = (float*) (ws + 0);            // 33,554,432
  bf16_t* ctx_bf  = (bf16_t*)(ws + 33554432ull);  // 16,777,216
  float*  qkv     = (float*) (ws + 50331648ull);  // 41,943,040 (reused as h f32)
  bf16_t* attn_bf = (bf16_t*)(ws + 92274688ull);  // 16,777,216 (reused as h bf16)
  float*  Gbuf    = (float*) (ws + 109051904ull); //  2,097,152
  float*  KSbuf   = (float*) (ws + 111149056ull); //     16,384
  bf16_t* WqkvT   = (bf16_t*)(ws + 111165440ull); //  2,621,440
  bf16_t* WoT     = (bf16_t*)(ws + 113786880ull); //  2,097,152
  bf16_t* outWT   = (bf16_t*)(ws + 115884032ull); // 65,536,000  (end 181,420,032)
  float*  hbuf    = qkv;
  bf16_t* h_bf    = attn_bf;

  transpose_cvt<<<dim3(2, 16),   256, 0, stream>>>(Wq,   WqkvT,              DD, 128);
  transpose_cvt<<<dim3(2, 16),   256, 0, stream>>>(Wk,   WqkvT + 128 * DD,   DD, 128);
  transpose_cvt<<<dim3(16, 16),  256, 0, stream>>>(Wv,   WqkvT + 256 * DD,   DD, DD);
  transpose_cvt<<<dim3(16, 16),  256, 0, stream>>>(Wo,   WoT,                DD, DD);
  transpose_cvt<<<dim3(500, 16), 256, 0, stream>>>(outW, outWT,              DD, VV);

  ctx_kernel<<<BB * SS, 256, 0, stream>>>(x, emb, ctx_f32, ctx_bf);

  gemm_bf16_kernel<0><<<dim3(QKVW / 128, BB * SS / 128), 256, 0, stream>>>(
      ctx_bf, WqkvT, qkv, nullptr, QKVW, DD);
  phi_kernel<<<BB * SS, 256, 0, stream>>>(qkv);

  gstate_kernel<<<BB * NC * HH, 256, 0, stream>>>(qkv, Gbuf, KSbuf);
  attn_kernel<<<BB * NC * HH * 2, 256, 0, stream>>>(qkv, Gbuf, KSbuf, attn_bf);

  gemm_bf16_kernel<2><<<dim3(DD / 128, BB * SS / 128), 256, 0, stream>>>(
      attn_bf, WoT, hbuf, ctx_f32, DD, DD);

  ln_kernel<<<BB * SS, 256, 0, stream>>>(hbuf, ln_g, ln_b, h_bf);

  gemm_bf16_kernel<1><<<dim3(VV / 128, BB * SS / 128), 256, 0, stream>>>(
      h_bf, outWT, out, outb, VV, DD);
}

// Round 3
// 1210.237 us; speedup vs baseline: 1.0792x; 1.0792x over previous
//
#include <hip/hip_runtime.h>
#include <hip/hip_bf16.h>

typedef __bf16 bf16_t;
typedef __bf16 bf16x4 __attribute__((ext_vector_type(4)));
typedef __bf16 bf16x8 __attribute__((ext_vector_type(8)));
typedef float f32x4 __attribute__((ext_vector_type(4)));

#define BB 2
#define SS 4096
#define DD 1024
#define VV 32000
#define HH 8
#define CC 256
#define NC 16
#define QKVW 1280   // q(128) | k(128) | v(1024)

#define GLD_LDS16(gp, lp) __builtin_amdgcn_global_load_lds( \
    (const __attribute__((address_space(1))) void*)(gp),    \
    (__attribute__((address_space(3))) void*)(lp), 16, 0, 0)

// ---------------- ctx: emb gather + 4-tap causal sum ----------------
__global__ __launch_bounds__(256) void ctx_kernel(
    const int* __restrict__ x, const float* __restrict__ emb,
    float* __restrict__ ctx, bf16_t* __restrict__ ctxb)
{
  const int row = blockIdx.x;            // b*SS + s
  const int b = row >> 12, s = row & (SS - 1);
  const int t = threadIdx.x;             // d = t*4
  float4 a = make_float4(0.f, 0.f, 0.f, 0.f);
  #pragma unroll
  for (int o = 0; o < 4; ++o) {
    if (s - o >= 0) {
      const int idx = x[b * SS + s - o];
      const float4 e = *(const float4*)(emb + (size_t)idx * DD + t * 4);
      a.x += e.x; a.y += e.y; a.z += e.z; a.w += e.w;
    }
  }
  *(float4*)(ctx + (size_t)row * DD + t * 4) = a;
  bf16x4 bv;
  bv[0] = (__bf16)a.x; bv[1] = (__bf16)a.y; bv[2] = (__bf16)a.z; bv[3] = (__bf16)a.w;
  *(bf16x4*)(ctxb + (size_t)row * DD + t * 4) = bv;
}

// ---------------- transpose + f32->bf16: dst[c][r] = src[r][c] ----------------
__global__ __launch_bounds__(256) void transpose_cvt(
    const float* __restrict__ src, bf16_t* __restrict__ dst,
    int srcRows, int srcCols)
{
  __shared__ __align__(16) float tile[64][65];
  const int c0 = blockIdx.x * 64, r0 = blockIdx.y * 64;
  const int tc = threadIdx.x & 63, tq = threadIdx.x >> 6;
  #pragma unroll
  for (int k = 0; k < 16; ++k) {
    const int r = k * 4 + tq;
    tile[r][tc] = src[(size_t)(r0 + r) * srcCols + c0 + tc];
  }
  __syncthreads();
  #pragma unroll
  for (int k = 0; k < 16; ++k) {
    const int cO = k * 4 + tq;
    dst[(size_t)(c0 + cO) * srcRows + r0 + tc] = (__bf16)tile[tc][cO];
  }
}

// ================= 256x256 tile, BK=64, 8-wave, 4-phase pipelined GEMM =======
// C[M,N] = A[M,K] @ BT[N,K]^T.  EPI: 0=none, 1=+bias[col], 2=+res, 3=phi(col<256)
// LDS XOR-swizzle (T2): logical (row,cg16B) lives at byte row*128 + (cg^(row&7))*16.
// global_load_lds dest stays linear; global source is pre-swizzled (rule #21).
// Staging cadence (quarters, 2 loads/thread/phase), tile k phases q0..q3:
//   q0: Aq13[k+1] -> buf[(k+1)&1]     q1: Bnh1[k+1] -> buf[(k+1)&1]
//   q2: Aq02[k+2] -> buf[k&1]         q3: Bnh0[k+2] -> buf[k&1], then vmcnt(4)
// Quadrant order (mh,nh): (0,0),(0,1),(1,0),(1,1). Per-wave rows wr*128+mh*64
// (so Aq{2wr} free after q1), B stripes nh*32 (Bnh0 free after q2).

#define STG_AQ02(SRC, RB, LDSB, KT) do {                                      \
  const size_t _k = (size_t)(KT) * 64;                                        \
  GLD_LDS16((SRC) + (size_t)((RB) + (t >> 3)) * K + _k + cg8,                 \
            (LDSB) + (size_t)(t & ~63) * 8);                                  \
  GLD_LDS16((SRC) + (size_t)((RB) + 128 + (t >> 3)) * K + _k + cg8,          \
            (LDSB) + 8192 + (size_t)(t & ~63) * 8);                           \
} while (0)

#define STG_AQ13(SRC, RB, LDSB, KT) do {                                      \
  const size_t _k = (size_t)(KT) * 64;                                        \
  GLD_LDS16((SRC) + (size_t)((RB) + 64 + (t >> 3)) * K + _k + cg8,           \
            (LDSB) + 4096 + (size_t)(t & ~63) * 8);                           \
  GLD_LDS16((SRC) + (size_t)((RB) + 192 + (t >> 3)) * K + _k + cg8,          \
            (LDSB) + 12288 + (size_t)(t & ~63) * 8);                          \
} while (0)

#define STG_BNH0(SRC, RB, LDSB, KT) do {                                      \
  const size_t _k = (size_t)(KT) * 64;                                        \
  const int _r = (t >> 3) + ((t >> 8) << 5);                                  \
  const int _u = ((t & ~63) + ((t >> 8) << 8)) * 8;                           \
  GLD_LDS16((SRC) + (size_t)((RB) + _r) * K + _k + cg8, (LDSB) + _u);        \
  GLD_LDS16((SRC) + (size_t)((RB) + 128 + _r) * K + _k + cg8,                \
            (LDSB) + 8192 + _u);                                              \
} while (0)

#define STG_BNH1(SRC, RB, LDSB, KT) do {                                      \
  const size_t _k = (size_t)(KT) * 64;                                        \
  const int _r = (t >> 3) + ((t >> 8) << 5);                                  \
  const int _u = ((t & ~63) + ((t >> 8) << 8)) * 8;                           \
  GLD_LDS16((SRC) + (size_t)((RB) + 32 + _r) * K + _k + cg8,                 \
            (LDSB) + 2048 + _u);                                              \
  GLD_LDS16((SRC) + (size_t)((RB) + 160 + _r) * K + _k + cg8,                \
            (LDSB) + 10240 + _u);                                             \
} while (0)

#define PHASE(MH, NH, STGCODE, WAITCODE) do {                                 \
  bf16x8 af[4][2], bfr[2][2];                                                 \
  _Pragma("unroll") for (int mi = 0; mi < 4; ++mi) {                          \
    const bf16_t* ap = Ac + (size_t)(wr * 128 + (MH) * 64 + mi * 16 + lr) * 64; \
    af[mi][0] = *(const bf16x8*)(ap + c0);                                    \
    af[mi][1] = *(const bf16x8*)(ap + c1);                                    \
  }                                                                           \
  _Pragma("unroll") for (int ni = 0; ni < 2; ++ni) {                          \
    const bf16_t* bp = Bc + (size_t)(wc * 64 + (NH) * 32 + ni * 16 + lr) * 64; \
    bfr[ni][0] = *(const bf16x8*)(bp + c0);                                   \
    bfr[ni][1] = *(const bf16x8*)(bp + c1);                                   \
  }                                                                           \
  STGCODE;                                                                    \
  __builtin_amdgcn_s_barrier();                                               \
  asm volatile("s_waitcnt lgkmcnt(0)" ::: "memory");                          \
  __builtin_amdgcn_sched_barrier(0);                                          \
  __builtin_amdgcn_s_setprio(1);                                              \
  _Pragma("unroll") for (int mi = 0; mi < 4; ++mi)                            \
    _Pragma("unroll") for (int ni = 0; ni < 2; ++ni) {                        \
      acc[(MH)*4+mi][(NH)*2+ni] = __builtin_amdgcn_mfma_f32_16x16x32_bf16(    \
          af[mi][0], bfr[ni][0], acc[(MH)*4+mi][(NH)*2+ni], 0, 0, 0);         \
      acc[(MH)*4+mi][(NH)*2+ni] = __builtin_amdgcn_mfma_f32_16x16x32_bf16(    \
          af[mi][1], bfr[ni][1], acc[(MH)*4+mi][(NH)*2+ni], 0, 0, 0);         \
    }                                                                         \
  __builtin_amdgcn_s_setprio(0);                                              \
  WAITCODE;                                                                   \
  __builtin_amdgcn_s_barrier();                                               \
} while (0)

template<int EPI>
__global__ __launch_bounds__(512, 2) void gemm256_kernel(
    const bf16_t* __restrict__ A, const bf16_t* __restrict__ BT,
    float* __restrict__ C, const float* __restrict__ extra,
    int N, int K, int GX)
{
  __shared__ __align__(16) bf16_t AsBuf[2][256 * 64];
  __shared__ __align__(16) bf16_t BsBuf[2][256 * 64];
  const int nwg = gridDim.x;
  const int bid = blockIdx.x;
  const int s = (bid & 7) * (nwg >> 3) + (bid >> 3);   // XCD swizzle (nwg%8==0)
  const int bx = s % GX, by = s / GX;
  const int n0 = bx * 256, m0 = by * 256;
  const int t = threadIdx.x;
  const int lane = t & 63, w = t >> 6;
  const int wr = w >> 2, wc = w & 3;
  const int lr = lane & 15, lq = lane >> 4;
  const int rx = lr & 7;
  const int c0 = ((0 + lq) ^ rx) * 8;                  // ks=0 read col (elems)
  const int c1 = ((4 + lq) ^ rx) * 8;                  // ks=1
  const int cg8 = (((t & 7) ^ ((t >> 3) & 7))) * 8;    // stage pre-swizzled col
  const int NT = K >> 6;                               // 16 K-tiles
  f32x4 acc[8][4] = {};

  // prologue: cadence-consistent issue of tiles 0,1 (12 loads), vmcnt(4)
  STG_AQ02(A,  m0, AsBuf[0], 0);
  STG_BNH0(BT, n0, BsBuf[0], 0);
  STG_AQ13(A,  m0, AsBuf[0], 0);
  STG_BNH1(BT, n0, BsBuf[0], 0);
  STG_AQ02(A,  m0, AsBuf[1], 1);
  STG_BNH0(BT, n0, BsBuf[1], 1);
  asm volatile("s_waitcnt vmcnt(4)" ::: "memory");
  __builtin_amdgcn_s_barrier();

  for (int k = 0; k < NT; ++k) {
    const bf16_t* Ac = AsBuf[k & 1];
    const bf16_t* Bc = BsBuf[k & 1];
    bf16_t* An = AsBuf[(k + 1) & 1];
    bf16_t* Bn = BsBuf[(k + 1) & 1];
    bf16_t* Ak = AsBuf[k & 1];
    bf16_t* Bk = BsBuf[k & 1];
    const bool s1 = (k + 1 < NT), s2 = (k + 2 < NT);
    PHASE(0, 0, if (s1) STG_AQ13(A, m0, An, k + 1), );
    PHASE(0, 1, if (s1) STG_BNH1(BT, n0, Bn, k + 1), );
    PHASE(1, 0, if (s2) STG_AQ02(A, m0, Ak, k + 2), );
    PHASE(1, 1, if (s2) STG_BNH0(BT, n0, Bk, k + 2),
          if (k < NT - 2) { asm volatile("s_waitcnt vmcnt(4)" ::: "memory"); }
          else if (k == NT - 2) { asm volatile("s_waitcnt vmcnt(0)" ::: "memory"); });
  }

  // epilogue: C/D layout col=lane&15, row=(lane>>4)*4+reg  [m89-verified]
  #pragma unroll
  for (int mi = 0; mi < 8; ++mi) {
    #pragma unroll
    for (int r = 0; r < 4; ++r) {
      const int row = m0 + wr * 128 + mi * 16 + lq * 4 + r;
      #pragma unroll
      for (int ni = 0; ni < 4; ++ni) {
        const int col = n0 + wc * 64 + ni * 16 + lr;
        float v = acc[mi][ni][r];
        if (EPI == 1) v += extra[col];
        if (EPI == 2) v += extra[(size_t)row * N + col];
        if (EPI == 3) { if (col < 256) v = v > 0.f ? v + 1.f : __expf(v); }
        C[(size_t)row * N + col] = v;
      }
    }
  }
}

// ---------------- per-chunk G = K^T V and ksum ----------------
__global__ __launch_bounds__(256) void gstate_kernel(
    const float* __restrict__ qkv, float* __restrict__ G, float* __restrict__ KS)
{
  const int g = blockIdx.x;                    // b*128 + c*8 + h
  const int h = g & 7, c = (g >> 3) & 15, b = g >> 7;
  const int t = threadIdx.x;
  const int i = t >> 4, dg = t & 15;           // k-index, 8-col group
  const int srcbase = b * SS + c * CC;
  __shared__ __align__(16) float k_lds[64][16];
  __shared__ __align__(16) float v_lds[64][128];
  float acc[8] = {0,0,0,0,0,0,0,0};
  float ks = 0.f;
  for (int st = 0; st < 4; ++st) {
    __syncthreads();
    { const int sl = t >> 2, i0 = (t & 3) * 4;
      *(float4*)&k_lds[sl][i0] =
        *(const float4*)(qkv + (size_t)(srcbase + st * 64 + sl) * QKVW + 128 + h * 16 + i0); }
    #pragma unroll
    for (int vv = 0; vv < 8; ++vv) {
      const int sl = (t >> 5) + vv * 8, col = (t & 31) * 4;
      *(float4*)&v_lds[sl][col] =
        *(const float4*)(qkv + (size_t)(srcbase + st * 64 + sl) * QKVW + 256 + h * 128 + col);
    }
    __syncthreads();
    for (int sl = 0; sl < 64; ++sl) {
      const float kv = k_lds[sl][i];
      if (dg == 0) ks += kv;
      const float4 va = *(const float4*)&v_lds[sl][dg * 8];
      const float4 vb = *(const float4*)&v_lds[sl][dg * 8 + 4];
      acc[0] = fmaf(kv, va.x, acc[0]); acc[1] = fmaf(kv, va.y, acc[1]);
      acc[2] = fmaf(kv, va.z, acc[2]); acc[3] = fmaf(kv, va.w, acc[3]);
      acc[4] = fmaf(kv, vb.x, acc[4]); acc[5] = fmaf(kv, vb.y, acc[5]);
      acc[6] = fmaf(kv, vb.z, acc[6]); acc[7] = fmaf(kv, vb.w, acc[7]);
    }
  }
  float* gp = G + ((size_t)(b * NC + c) * HH + h) * 2048 + i * 128 + dg * 8;
  *(float4*)gp       = make_float4(acc[0], acc[1], acc[2], acc[3]);
  *(float4*)(gp + 4) = make_float4(acc[4], acc[5], acc[6], acc[7]);
  if (dg == 0) KS[((size_t)(b * NC + c) * HH + h) * 16 + i] = ks;
}

// ---------------- attention: intra (masked) + bypass (prev chunk) + state ----------------
__global__ __launch_bounds__(256) void attn_kernel(
    const float* __restrict__ qkv, const float* __restrict__ Gb,
    const float* __restrict__ KS, bf16_t* __restrict__ outp)
{
  const int bid = blockIdx.x;                   // 512 = b*256 + c*16 + h*2 + dh
  const int dh = bid & 1, h = (bid >> 1) & 7, c = (bid >> 4) & 15, b = bid >> 8;
  const int t = threadIdx.x;
  const int cg = t & 3, rg = t >> 2;            // 16-col group, 4-row group
  const int rowbase = b * SS + c * CC;

  __shared__ __align__(16) float k_lds[64][16];
  __shared__ __align__(16) float v_lds[64][64];
  __shared__ __align__(16) float s_lds[16 * 64];
  __shared__ float z_lds[16];

  float q[4][16];
  #pragma unroll
  for (int rr = 0; rr < 4; ++rr) {
    const float* qp = qkv + (size_t)(rowbase + rg * 4 + rr) * QKVW + h * 16;
    #pragma unroll
    for (int i4 = 0; i4 < 4; ++i4) {
      const float4 qv = *(const float4*)(qp + i4 * 4);
      q[rr][i4*4+0] = qv.x; q[rr][i4*4+1] = qv.y; q[rr][i4*4+2] = qv.z; q[rr][i4*4+3] = qv.w;
    }
  }
  float acc[4][16] = {};
  float den[4] = {0.f, 0.f, 0.f, 0.f};

  for (int ph = 0; ph < 2; ++ph) {
    const int cc = c - ph;                       // ph0: current chunk (masked); ph1: prev chunk
    if (cc < 0) break;
    const int srcbase = b * SS + cc * CC;
    const bool masked = (ph == 0);
    for (int st = 0; st < 4; ++st) {
      __syncthreads();
      { const int sl = t >> 2, i0 = (t & 3) * 4;
        *(float4*)&k_lds[sl][i0] =
          *(const float4*)(qkv + (size_t)(srcbase + st * 64 + sl) * QKVW + 128 + h * 16 + i0); }
      #pragma unroll
      for (int vv = 0; vv < 4; ++vv) {
        const int sl = (t >> 4) + vv * 16, col = (t & 15) * 4;
        *(float4*)&v_lds[sl][col] =
          *(const float4*)(qkv + (size_t)(srcbase + st * 64 + sl) * QKVW + 256 + h * 128 + dh * 64 + col);
      }
      __syncthreads();
      for (int sl = 0; sl < 64; ++sl) {
        float kv[16], vvv[16];
        #pragma unroll
        for (int i4 = 0; i4 < 4; ++i4) {
          const float4 kf = *(const float4*)&k_lds[sl][i4 * 4];
          kv[i4*4+0] = kf.x; kv[i4*4+1] = kf.y; kv[i4*4+2] = kf.z; kv[i4*4+3] = kf.w;
          const float4 vf = *(const float4*)&v_lds[sl][cg * 16 + i4 * 4];
          vvv[i4*4+0] = vf.x; vvv[i4*4+1] = vf.y; vvv[i4*4+2] = vf.z; vvv[i4*4+3] = vf.w;
        }
        const int sidx = st * 64 + sl;
        #pragma unroll
        for (int rr = 0; rr < 4; ++rr) {
          float a = 0.f;
          #pragma unroll
          for (int i = 0; i < 16; ++i) a = fmaf(q[rr][i], kv[i], a);
          if (masked && sidx > rg * 4 + rr) a = 0.f;
          den[rr] += a;                          // intra: q.kcum ; bypass: q.bksum
          #pragma unroll
          for (int e = 0; e < 16; ++e) acc[rr][e] = fmaf(a, vvv[e], acc[rr][e]);
        }
      }
    }
  }

  if (c >= 2) {                                  // long-range state: sum_{j<=c-2} G_j
    float sa0 = 0.f, sa1 = 0.f, sa2 = 0.f, sa3 = 0.f;
    const int si = t >> 4, sc = (t & 15) * 4;
    for (int j = 0; j + 2 <= c; ++j) {
      const float4 gv = *(const float4*)(Gb + ((size_t)(b * NC + j) * HH + h) * 2048
                                            + si * 128 + dh * 64 + sc);
      sa0 += gv.x; sa1 += gv.y; sa2 += gv.z; sa3 += gv.w;
    }
    if (t < 16) {
      float z = 0.f;
      for (int j = 0; j + 2 <= c; ++j) z += KS[((size_t)(b * NC + j) * HH + h) * 16 + t];
      z_lds[t] = z;
    }
    *(float4*)&s_lds[si * 64 + sc] = make_float4(sa0, sa1, sa2, sa3);
    __syncthreads();
    #pragma unroll
    for (int i = 0; i < 16; ++i) {
      float sv[16];
      #pragma unroll
      for (int e4 = 0; e4 < 4; ++e4) {
        const float4 f = *(const float4*)&s_lds[i * 64 + cg * 16 + e4 * 4];
        sv[e4*4+0] = f.x; sv[e4*4+1] = f.y; sv[e4*4+2] = f.z; sv[e4*4+3] = f.w;
      }
      const float zi = z_lds[i];
      #pragma unroll
      for (int rr = 0; rr < 4; ++rr) {
        const float qv = q[rr][i];
        den[rr] = fmaf(qv, zi, den[rr]);
        #pragma unroll
        for (int e = 0; e < 16; ++e) acc[rr][e] = fmaf(qv, sv[e], acc[rr][e]);
      }
    }
  }

  const size_t obase = (size_t)rowbase * DD + h * 128 + dh * 64 + cg * 16;
  #pragma unroll
  for (int rr = 0; rr < 4; ++rr) {
    const float inv = 1.0f / (den[rr] + 1e-6f);
    bf16_t* op = outp + obase + (size_t)(rg * 4 + rr) * DD;
    #pragma unroll
    for (int e4 = 0; e4 < 4; ++e4) {
      bf16x4 bv;
      bv[0] = (__bf16)(acc[rr][e4*4+0] * inv); bv[1] = (__bf16)(acc[rr][e4*4+1] * inv);
      bv[2] = (__bf16)(acc[rr][e4*4+2] * inv); bv[3] = (__bf16)(acc[rr][e4*4+3] * inv);
      *(bf16x4*)(op + e4 * 4) = bv;
    }
  }
}

// ---------------- LayerNorm (eps 1e-5) -> bf16 ----------------
__global__ __launch_bounds__(256) void ln_kernel(
    const float* __restrict__ hbuf, const float* __restrict__ g,
    const float* __restrict__ bta, bf16_t* __restrict__ out)
{
  const int row = blockIdx.x;
  const int t = threadIdx.x;
  const float4 x = ((const float4*)(hbuf + (size_t)row * DD))[t];
  float s  = x.x + x.y + x.z + x.w;
  float s2 = x.x*x.x + x.y*x.y + x.z*x.z + x.w*x.w;
  #pragma unroll
  for (int off = 32; off > 0; off >>= 1) {
    s  += __shfl_down(s,  off, 64);
    s2 += __shfl_down(s2, off, 64);
  }
  __shared__ float ws[8];
  if ((t & 63) == 0) { ws[(t >> 6) * 2] = s; ws[(t >> 6) * 2 + 1] = s2; }
  __syncthreads();
  const float ts  = ws[0] + ws[2] + ws[4] + ws[6];
  const float ts2 = ws[1] + ws[3] + ws[5] + ws[7];
  const float mu  = ts * (1.0f / DD);
  const float var = ts2 * (1.0f / DD) - mu * mu;
  const float inv = rsqrtf(var + 1e-5f);
  const float4 gv = ((const float4*)g)[t];
  const float4 bv = ((const float4*)bta)[t];
  bf16x4 o;
  o[0] = (__bf16)((x.x - mu) * inv * gv.x + bv.x);
  o[1] = (__bf16)((x.y - mu) * inv * gv.y + bv.y);
  o[2] = (__bf16)((x.z - mu) * inv * gv.z + bv.z);
  o[3] = (__bf16)((x.w - mu) * inv * gv.w + bv.w);
  *(bf16x4*)(out + (size_t)row * DD + t * 4) = o;
}

extern "C" void kernel_launch(void* const* d_in, const int* in_sizes, int n_in,
                              void* d_out, int out_size, void* d_ws, size_t ws_size,
                              hipStream_t stream) {
  (void)in_sizes; (void)n_in; (void)out_size; (void)ws_size;
  const int*   x    = (const int*)d_in[0];
  const float* emb  = (const float*)d_in[1];
  const float* Wq   = (const float*)d_in[2];
  const float* Wk   = (const float*)d_in[3];
  const float* Wv   = (const float*)d_in[4];
  const float* Wo   = (const float*)d_in[5];
  const float* ln_g = (const float*)d_in[6];
  const float* ln_b = (const float*)d_in[7];
  const float* outW = (const float*)d_in[8];
  const float* outb = (const float*)d_in[9];
  float* out = (float*)d_out;

  char* ws = (char*)d_ws;
  float*  ctx_f32 = (float*) (ws + 0);            // 33,554,432
  bf16_t* ctx_bf  = (bf16_t*)(ws + 33554432ull);  // 16,777,216
  float*  qkv     = (float*) (ws + 50331648ull);  // 41,943,040 (reused as h f32)
  bf16_t* attn_bf = (bf16_t*)(ws + 92274688ull);  // 16,777,216 (reused as h bf16)
  float*  Gbuf    = (float*) (ws + 109051904ull); //  2,097,152
  float*  KSbuf   = (float*) (ws + 111149056ull); //     16,384
  bf16_t* WqkvT   = (bf16_t*)(ws + 111165440ull); //  2,621,440
  bf16_t* WoT     = (bf16_t*)(ws + 113786880ull); //  2,097,152
  bf16_t* outWT   = (bf16_t*)(ws + 115884032ull); // 65,536,000  (end 181,420,032)
  float*  hbuf    = qkv;
  bf16_t* h_bf    = attn_bf;

  transpose_cvt<<<dim3(2, 16),   256, 0, stream>>>(Wq,   WqkvT,              DD, 128);
  transpose_cvt<<<dim3(2, 16),   256, 0, stream>>>(Wk,   WqkvT + 128 * DD,   DD, 128);
  transpose_cvt<<<dim3(16, 16),  256, 0, stream>>>(Wv,   WqkvT + 256 * DD,   DD, DD);
  transpose_cvt<<<dim3(16, 16),  256, 0, stream>>>(Wo,   WoT,                DD, DD);
  transpose_cvt<<<dim3(500, 16), 256, 0, stream>>>(outW, outWT,              DD, VV);

  ctx_kernel<<<BB * SS, 256, 0, stream>>>(x, emb, ctx_f32, ctx_bf);

  // QKV projection + fused phi on cols<256  (M=8192, N=1280, grid 5*32=160)
  gemm256_kernel<3><<<(QKVW / 256) * (BB * SS / 256), 512, 0, stream>>>(
      ctx_bf, WqkvT, qkv, nullptr, QKVW, DD, QKVW / 256);

  gstate_kernel<<<BB * NC * HH, 256, 0, stream>>>(qkv, Gbuf, KSbuf);
  attn_kernel<<<BB * NC * HH * 2, 256, 0, stream>>>(qkv, Gbuf, KSbuf, attn_bf);

  // out-proj + residual  (N=1024, grid 4*32=128)
  gemm256_kernel<2><<<(DD / 256) * (BB * SS / 256), 512, 0, stream>>>(
      attn_bf, WoT, hbuf, ctx_f32, DD, DD, DD / 256);

  ln_kernel<<<BB * SS, 256, 0, stream>>>(hbuf, ln_g, ln_b, h_bf);

  // logits + bias  (N=32000, grid 125*32=4000)
  gemm256_kernel<1><<<(VV / 256) * (BB * SS / 256), 512, 0, stream>>>(
      h_bf, outWT, out, outb, VV, DD, VV / 256);
}

// Round 4
// 1160.345 us; speedup vs baseline: 1.1256x; 1.0430x over previous
//
#include <hip/hip_runtime.h>
#include <hip/hip_bf16.h>

typedef __bf16 bf16_t;
typedef __bf16 bf16x4 __attribute__((ext_vector_type(4)));
typedef __bf16 bf16x8 __attribute__((ext_vector_type(8)));
typedef float f32x4 __attribute__((ext_vector_type(4)));

#define BB 2
#define SS 4096
#define DD 1024
#define VV 32000
#define HH 8
#define CC 256
#define NC 16
#define QKVW 1280   // q(128) | k(128) | v(1024)

#define GLD_LDS16(gp, lp) __builtin_amdgcn_global_load_lds( \
    (const __attribute__((address_space(1))) void*)(gp),    \
    (__attribute__((address_space(3))) void*)(lp), 16, 0, 0)

// ---------------- ctx: emb gather + 4-tap causal sum ----------------
__global__ __launch_bounds__(256) void ctx_kernel(
    const int* __restrict__ x, const float* __restrict__ emb,
    float* __restrict__ ctx, bf16_t* __restrict__ ctxb)
{
  const int row = blockIdx.x;            // b*SS + s
  const int b = row >> 12, s = row & (SS - 1);
  const int t = threadIdx.x;             // d = t*4
  float4 a = make_float4(0.f, 0.f, 0.f, 0.f);
  #pragma unroll
  for (int o = 0; o < 4; ++o) {
    if (s - o >= 0) {
      const int idx = x[b * SS + s - o];
      const float4 e = *(const float4*)(emb + (size_t)idx * DD + t * 4);
      a.x += e.x; a.y += e.y; a.z += e.z; a.w += e.w;
    }
  }
  *(float4*)(ctx + (size_t)row * DD + t * 4) = a;
  bf16x4 bv;
  bv[0] = (__bf16)a.x; bv[1] = (__bf16)a.y; bv[2] = (__bf16)a.z; bv[3] = (__bf16)a.w;
  *(bf16x4*)(ctxb + (size_t)row * DD + t * 4) = bv;
}

// ---------------- transpose + f32->bf16: dst[c][r] = src[r][c] ----------------
__global__ __launch_bounds__(256) void transpose_cvt(
    const float* __restrict__ src, bf16_t* __restrict__ dst,
    int srcRows, int srcCols)
{
  __shared__ __align__(16) float tile[64][65];
  const int c0 = blockIdx.x * 64, r0 = blockIdx.y * 64;
  const int tc = threadIdx.x & 63, tq = threadIdx.x >> 6;
  #pragma unroll
  for (int k = 0; k < 16; ++k) {
    const int r = k * 4 + tq;
    tile[r][tc] = src[(size_t)(r0 + r) * srcCols + c0 + tc];
  }
  __syncthreads();
  #pragma unroll
  for (int k = 0; k < 16; ++k) {
    const int cO = k * 4 + tq;
    dst[(size_t)(c0 + cO) * srcRows + r0 + tc] = (__bf16)tile[tc][cO];
  }
}

// ================= 256x256 tile, BK=64, 8-wave, 4-phase pipelined GEMM =======
// C[M,N] = A[M,K] @ BT[N,K]^T.  EPI: 0=none, 1=+bias[col], 2=+res, 3=phi(col<256)
// R4 change: B fragments K-tile-resident (read once), A quadrant-resident ->
// 24 ds_read_b128 per wave per K-tile (was 48) — LDS read BW was the binding
// constraint (R3: MfmaUtil 29% with 0 bank conflicts, VALUBusy 16%).
// Staging cadence (quarters, 2 loads/thread each), tile k phases q0..q3:
//   q0: Aq13[k+1] -> buf^1   q1: Bnh1[k+1] -> buf^1
//   q2: Aq02[k+2] -> buf     q3: Bnh0[k+2] -> buf, then vmcnt(4)
// Reads: q0: A_MH0(8) + B n0,n1(4); q1: B n2,n3(4); q2: A_MH1(8); q3: none.
// Region safety: each staged region's last ds_read retired >=1 barrier earlier.

#define STG_AQ02(SRC, RB, LDSB, KT) do {                                      \
  const size_t _k = (size_t)(KT) * 64;                                        \
  GLD_LDS16((SRC) + (size_t)((RB) + (t >> 3)) * K + _k + cg8,                 \
            (LDSB) + (size_t)(t & ~63) * 8);                                  \
  GLD_LDS16((SRC) + (size_t)((RB) + 128 + (t >> 3)) * K + _k + cg8,          \
            (LDSB) + 8192 + (size_t)(t & ~63) * 8);                           \
} while (0)

#define STG_AQ13(SRC, RB, LDSB, KT) do {                                      \
  const size_t _k = (size_t)(KT) * 64;                                        \
  GLD_LDS16((SRC) + (size_t)((RB) + 64 + (t >> 3)) * K + _k + cg8,           \
            (LDSB) + 4096 + (size_t)(t & ~63) * 8);                           \
  GLD_LDS16((SRC) + (size_t)((RB) + 192 + (t >> 3)) * K + _k + cg8,          \
            (LDSB) + 12288 + (size_t)(t & ~63) * 8);                          \
} while (0)

#define STG_BNH0(SRC, RB, LDSB, KT) do {                                      \
  const size_t _k = (size_t)(KT) * 64;                                        \
  const int _r = (t >> 3) + ((t >> 8) << 5);                                  \
  const int _u = ((t & ~63) + ((t >> 8) << 8)) * 8;                           \
  GLD_LDS16((SRC) + (size_t)((RB) + _r) * K + _k + cg8, (LDSB) + _u);        \
  GLD_LDS16((SRC) + (size_t)((RB) + 128 + _r) * K + _k + cg8,                \
            (LDSB) + 8192 + _u);                                              \
} while (0)

#define STG_BNH1(SRC, RB, LDSB, KT) do {                                      \
  const size_t _k = (size_t)(KT) * 64;                                        \
  const int _r = (t >> 3) + ((t >> 8) << 5);                                  \
  const int _u = ((t & ~63) + ((t >> 8) << 8)) * 8;                           \
  GLD_LDS16((SRC) + (size_t)((RB) + 32 + _r) * K + _k + cg8,                 \
            (LDSB) + 2048 + _u);                                              \
  GLD_LDS16((SRC) + (size_t)((RB) + 160 + _r) * K + _k + cg8,                \
            (LDSB) + 10240 + _u);                                             \
} while (0)

#define READ_A(MH) do {                                                       \
  _Pragma("unroll") for (int mi = 0; mi < 4; ++mi) {                          \
    const bf16_t* ap = Ac + (size_t)(wr * 128 + (MH) * 64 + mi * 16 + lr) * 64; \
    af[mi][0] = *(const bf16x8*)(ap + c0);                                    \
    af[mi][1] = *(const bf16x8*)(ap + c1);                                    \
  } } while (0)

#define READ_B2(NB) do {                                                      \
  _Pragma("unroll") for (int nj = 0; nj < 2; ++nj) {                          \
    const bf16_t* bp = Bc + (size_t)(wc * 64 + ((NB) + nj) * 16 + lr) * 64;   \
    bfr[(NB) + nj][0] = *(const bf16x8*)(bp + c0);                            \
    bfr[(NB) + nj][1] = *(const bf16x8*)(bp + c1);                            \
  } } while (0)

#define MFMA8(MH, NB) do {                                                    \
  _Pragma("unroll") for (int mi = 0; mi < 4; ++mi)                            \
    _Pragma("unroll") for (int nj = 0; nj < 2; ++nj) {                        \
      acc[(MH)*4+mi][(NB)+nj] = __builtin_amdgcn_mfma_f32_16x16x32_bf16(      \
          af[mi][0], bfr[(NB)+nj][0], acc[(MH)*4+mi][(NB)+nj], 0, 0, 0);      \
      acc[(MH)*4+mi][(NB)+nj] = __builtin_amdgcn_mfma_f32_16x16x32_bf16(      \
          af[mi][1], bfr[(NB)+nj][1], acc[(MH)*4+mi][(NB)+nj], 0, 0, 0);      \
    } } while (0)

#define PH_SYNC() do {                                                        \
  __builtin_amdgcn_s_barrier();                                               \
  asm volatile("s_waitcnt lgkmcnt(0)" ::: "memory");                          \
  __builtin_amdgcn_sched_barrier(0);                                          \
} while (0)

template<int EPI>
__global__ __launch_bounds__(512, 2) void gemm256_kernel(
    const bf16_t* __restrict__ A, const bf16_t* __restrict__ BT,
    float* __restrict__ C, const float* __restrict__ extra,
    int N, int K, int GX)
{
  __shared__ __align__(16) bf16_t AsBuf[2][256 * 64];
  __shared__ __align__(16) bf16_t BsBuf[2][256 * 64];
  const int nwg = gridDim.x;
  const int bid = blockIdx.x;
  const int s = (bid & 7) * (nwg >> 3) + (bid >> 3);   // XCD swizzle (nwg%8==0)
  const int bx = s % GX, by = s / GX;
  const int n0 = bx * 256, m0 = by * 256;
  const int t = threadIdx.x;
  const int lane = t & 63, w = t >> 6;
  const int wr = w >> 2, wc = w & 3;
  const int lr = lane & 15, lq = lane >> 4;
  const int rx = lr & 7;
  const int c0 = ((0 + lq) ^ rx) * 8;                  // ks=0 read col (elems)
  const int c1 = ((4 + lq) ^ rx) * 8;                  // ks=1
  const int cg8 = (((t & 7) ^ ((t >> 3) & 7))) * 8;    // stage pre-swizzled col
  const int NT = K >> 6;                               // K-tiles
  f32x4 acc[8][4] = {};

  // prologue: cadence-consistent issue of tiles 0,1 (12 loads), vmcnt(4)
  STG_AQ02(A,  m0, AsBuf[0], 0);
  STG_BNH0(BT, n0, BsBuf[0], 0);
  STG_AQ13(A,  m0, AsBuf[0], 0);
  STG_BNH1(BT, n0, BsBuf[0], 0);
  STG_AQ02(A,  m0, AsBuf[1], 1);
  STG_BNH0(BT, n0, BsBuf[1], 1);
  asm volatile("s_waitcnt vmcnt(4)" ::: "memory");
  __builtin_amdgcn_s_barrier();

  for (int k = 0; k < NT; ++k) {
    const bf16_t* Ac = AsBuf[k & 1];
    const bf16_t* Bc = BsBuf[k & 1];
    bf16_t* An = AsBuf[(k + 1) & 1];
    bf16_t* Bn = BsBuf[(k + 1) & 1];
    bf16_t* Ak = AsBuf[k & 1];
    bf16_t* Bk = BsBuf[k & 1];
    const bool s1 = (k + 1 < NT), s2 = (k + 2 < NT);
    bf16x8 af[4][2], bfr[4][2];
    // ---- q0: read A_MH0 + B n0,n1; stage Aq13[k+1]
    READ_A(0); READ_B2(0);
    if (s1) STG_AQ13(A, m0, An, k + 1);
    PH_SYNC();
    __builtin_amdgcn_s_setprio(1);
    MFMA8(0, 0);
    __builtin_amdgcn_s_setprio(0);
    __builtin_amdgcn_s_barrier();
    // ---- q1: read B n2,n3; stage Bnh1[k+1]
    READ_B2(2);
    if (s1) STG_BNH1(BT, n0, Bn, k + 1);
    PH_SYNC();
    __builtin_amdgcn_s_setprio(1);
    MFMA8(0, 2);
    __builtin_amdgcn_s_setprio(0);
    __builtin_amdgcn_s_barrier();
    // ---- q2: read A_MH1; stage Aq02[k+2]
    READ_A(1);
    if (s2) STG_AQ02(A, m0, Ak, k + 2);
    PH_SYNC();
    __builtin_amdgcn_s_setprio(1);
    MFMA8(1, 0);
    __builtin_amdgcn_s_setprio(0);
    __builtin_amdgcn_s_barrier();
    // ---- q3: register-only MFMA; stage Bnh0[k+2]; counted vmcnt
    if (s2) STG_BNH0(BT, n0, Bk, k + 2);
    __builtin_amdgcn_s_setprio(1);
    MFMA8(1, 2);
    __builtin_amdgcn_s_setprio(0);
    if (k < NT - 2) { asm volatile("s_waitcnt vmcnt(4)" ::: "memory"); }
    else if (k == NT - 2) { asm volatile("s_waitcnt vmcnt(0)" ::: "memory"); }
    __builtin_amdgcn_s_barrier();
  }

  // epilogue: C/D layout col=lane&15, row=(lane>>4)*4+reg  [m89-verified]
  #pragma unroll
  for (int mi = 0; mi < 8; ++mi) {
    #pragma unroll
    for (int r = 0; r < 4; ++r) {
      const int row = m0 + wr * 128 + mi * 16 + lq * 4 + r;
      #pragma unroll
      for (int ni = 0; ni < 4; ++ni) {
        const int col = n0 + wc * 64 + ni * 16 + lr;
        float v = acc[mi][ni][r];
        if (EPI == 1) v += extra[col];
        if (EPI == 2) v += extra[(size_t)row * N + col];
        if (EPI == 3) { if (col < 256) v = v > 0.f ? v + 1.f : __expf(v); }
        C[(size_t)row * N + col] = v;
      }
    }
  }
}

// ---------------- per-chunk G = K^T V and ksum ----------------
__global__ __launch_bounds__(256) void gstate_kernel(
    const float* __restrict__ qkv, float* __restrict__ G, float* __restrict__ KS)
{
  const int g = blockIdx.x;                    // b*128 + c*8 + h
  const int h = g & 7, c = (g >> 3) & 15, b = g >> 7;
  const int t = threadIdx.x;
  const int i = t >> 4, dg = t & 15;           // k-index, 8-col group
  const int srcbase = b * SS + c * CC;
  __shared__ __align__(16) float k_lds[64][16];
  __shared__ __align__(16) float v_lds[64][128];
  float acc[8] = {0,0,0,0,0,0,0,0};
  float ks = 0.f;
  for (int st = 0; st < 4; ++st) {
    __syncthreads();
    { const int sl = t >> 2, i0 = (t & 3) * 4;
      *(float4*)&k_lds[sl][i0] =
        *(const float4*)(qkv + (size_t)(srcbase + st * 64 + sl) * QKVW + 128 + h * 16 + i0); }
    #pragma unroll
    for (int vv = 0; vv < 8; ++vv) {
      const int sl = (t >> 5) + vv * 8, col = (t & 31) * 4;
      *(float4*)&v_lds[sl][col] =
        *(const float4*)(qkv + (size_t)(srcbase + st * 64 + sl) * QKVW + 256 + h * 128 + col);
    }
    __syncthreads();
    for (int sl = 0; sl < 64; ++sl) {
      const float kv = k_lds[sl][i];
      if (dg == 0) ks += kv;
      const float4 va = *(const float4*)&v_lds[sl][dg * 8];
      const float4 vb = *(const float4*)&v_lds[sl][dg * 8 + 4];
      acc[0] = fmaf(kv, va.x, acc[0]); acc[1] = fmaf(kv, va.y, acc[1]);
      acc[2] = fmaf(kv, va.z, acc[2]); acc[3] = fmaf(kv, va.w, acc[3]);
      acc[4] = fmaf(kv, vb.x, acc[4]); acc[5] = fmaf(kv, vb.y, acc[5]);
      acc[6] = fmaf(kv, vb.z, acc[6]); acc[7] = fmaf(kv, vb.w, acc[7]);
    }
  }
  float* gp = G + ((size_t)(b * NC + c) * HH + h) * 2048 + i * 128 + dg * 8;
  *(float4*)gp       = make_float4(acc[0], acc[1], acc[2], acc[3]);
  *(float4*)(gp + 4) = make_float4(acc[4], acc[5], acc[6], acc[7]);
  if (dg == 0) KS[((size_t)(b * NC + c) * HH + h) * 16 + i] = ks;
}

// ---------------- attention: intra (masked) + bypass (prev chunk) + state ----------------
__global__ __launch_bounds__(256) void attn_kernel(
    const float* __restrict__ qkv, const float* __restrict__ Gb,
    const float* __restrict__ KS, bf16_t* __restrict__ outp)
{
  const int bid = blockIdx.x;                   // 512 = b*256 + c*16 + h*2 + dh
  const int dh = bid & 1, h = (bid >> 1) & 7, c = (bid >> 4) & 15, b = bid >> 8;
  const int t = threadIdx.x;
  const int cg = t & 3, rg = t >> 2;            // 16-col group, 4-row group
  const int rowbase = b * SS + c * CC;

  __shared__ __align__(16) float k_lds[64][16];
  __shared__ __align__(16) float v_lds[64][64];
  __shared__ __align__(16) float s_lds[16 * 64];
  __shared__ float z_lds[16];

  float q[4][16];
  #pragma unroll
  for (int rr = 0; rr < 4; ++rr) {
    const float* qp = qkv + (size_t)(rowbase + rg * 4 + rr) * QKVW + h * 16;
    #pragma unroll
    for (int i4 = 0; i4 < 4; ++i4) {
      const float4 qv = *(const float4*)(qp + i4 * 4);
      q[rr][i4*4+0] = qv.x; q[rr][i4*4+1] = qv.y; q[rr][i4*4+2] = qv.z; q[rr][i4*4+3] = qv.w;
    }
  }
  float acc[4][16] = {};
  float den[4] = {0.f, 0.f, 0.f, 0.f};

  for (int ph = 0; ph < 2; ++ph) {
    const int cc = c - ph;                       // ph0: current chunk (masked); ph1: prev chunk
    if (cc < 0) break;
    const int srcbase = b * SS + cc * CC;
    const bool masked = (ph == 0);
    for (int st = 0; st < 4; ++st) {
      __syncthreads();
      { const int sl = t >> 2, i0 = (t & 3) * 4;
        *(float4*)&k_lds[sl][i0] =
          *(const float4*)(qkv + (size_t)(srcbase + st * 64 + sl) * QKVW + 128 + h * 16 + i0); }
      #pragma unroll
      for (int vv = 0; vv < 4; ++vv) {
        const int sl = (t >> 4) + vv * 16, col = (t & 15) * 4;
        *(float4*)&v_lds[sl][col] =
          *(const float4*)(qkv + (size_t)(srcbase + st * 64 + sl) * QKVW + 256 + h * 128 + dh * 64 + col);
      }
      __syncthreads();
      for (int sl = 0; sl < 64; ++sl) {
        float kv[16], vvv[16];
        #pragma unroll
        for (int i4 = 0; i4 < 4; ++i4) {
          const float4 kf = *(const float4*)&k_lds[sl][i4 * 4];
          kv[i4*4+0] = kf.x; kv[i4*4+1] = kf.y; kv[i4*4+2] = kf.z; kv[i4*4+3] = kf.w;
          const float4 vf = *(const float4*)&v_lds[sl][cg * 16 + i4 * 4];
          vvv[i4*4+0] = vf.x; vvv[i4*4+1] = vf.y; vvv[i4*4+2] = vf.z; vvv[i4*4+3] = vf.w;
        }
        const int sidx = st * 64 + sl;
        #pragma unroll
        for (int rr = 0; rr < 4; ++rr) {
          float a = 0.f;
          #pragma unroll
          for (int i = 0; i < 16; ++i) a = fmaf(q[rr][i], kv[i], a);
          if (masked && sidx > rg * 4 + rr) a = 0.f;
          den[rr] += a;                          // intra: q.kcum ; bypass: q.bksum
          #pragma unroll
          for (int e = 0; e < 16; ++e) acc[rr][e] = fmaf(a, vvv[e], acc[rr][e]);
        }
      }
    }
  }

  if (c >= 2) {                                  // long-range state: sum_{j<=c-2} G_j
    float sa0 = 0.f, sa1 = 0.f, sa2 = 0.f, sa3 = 0.f;
    const int si = t >> 4, sc = (t & 15) * 4;
    for (int j = 0; j + 2 <= c; ++j) {
      const float4 gv = *(const float4*)(Gb + ((size_t)(b * NC + j) * HH + h) * 2048
                                            + si * 128 + dh * 64 + sc);
      sa0 += gv.x; sa1 += gv.y; sa2 += gv.z; sa3 += gv.w;
    }
    if (t < 16) {
      float z = 0.f;
      for (int j = 0; j + 2 <= c; ++j) z += KS[((size_t)(b * NC + j) * HH + h) * 16 + t];
      z_lds[t] = z;
    }
    *(float4*)&s_lds[si * 64 + sc] = make_float4(sa0, sa1, sa2, sa3);
    __syncthreads();
    #pragma unroll
    for (int i = 0; i < 16; ++i) {
      float sv[16];
      #pragma unroll
      for (int e4 = 0; e4 < 4; ++e4) {
        const float4 f = *(const float4*)&s_lds[i * 64 + cg * 16 + e4 * 4];
        sv[e4*4+0] = f.x; sv[e4*4+1] = f.y; sv[e4*4+2] = f.z; sv[e4*4+3] = f.w;
      }
      const float zi = z_lds[i];
      #pragma unroll
      for (int rr = 0; rr < 4; ++rr) {
        const float qv = q[rr][i];
        den[rr] = fmaf(qv, zi, den[rr]);
        #pragma unroll
        for (int e = 0; e < 16; ++e) acc[rr][e] = fmaf(qv, sv[e], acc[rr][e]);
      }
    }
  }

  const size_t obase = (size_t)rowbase * DD + h * 128 + dh * 64 + cg * 16;
  #pragma unroll
  for (int rr = 0; rr < 4; ++rr) {
    const float inv = 1.0f / (den[rr] + 1e-6f);
    bf16_t* op = outp + obase + (size_t)(rg * 4 + rr) * DD;
    #pragma unroll
    for (int e4 = 0; e4 < 4; ++e4) {
      bf16x4 bv;
      bv[0] = (__bf16)(acc[rr][e4*4+0] * inv); bv[1] = (__bf16)(acc[rr][e4*4+1] * inv);
      bv[2] = (__bf16)(acc[rr][e4*4+2] * inv); bv[3] = (__bf16)(acc[rr][e4*4+3] * inv);
      *(bf16x4*)(op + e4 * 4) = bv;
    }
  }
}

// ---------------- LayerNorm (eps 1e-5) -> bf16 ----------------
__global__ __launch_bounds__(256) void ln_kernel(
    const float* __restrict__ hbuf, const float* __restrict__ g,
    const float* __restrict__ bta, bf16_t* __restrict__ out)
{
  const int row = blockIdx.x;
  const int t = threadIdx.x;
  const float4 x = ((const float4*)(hbuf + (size_t)row * DD))[t];
  float s  = x.x + x.y + x.z + x.w;
  float s2 = x.x*x.x + x.y*x.y + x.z*x.z + x.w*x.w;
  #pragma unroll
  for (int off = 32; off > 0; off >>= 1) {
    s  += __shfl_down(s,  off, 64);
    s2 += __shfl_down(s2, off, 64);
  }
  __shared__ float ws[8];
  if ((t & 63) == 0) { ws[(t >> 6) * 2] = s; ws[(t >> 6) * 2 + 1] = s2; }
  __syncthreads();
  const float ts  = ws[0] + ws[2] + ws[4] + ws[6];
  const float ts2 = ws[1] + ws[3] + ws[5] + ws[7];
  const float mu  = ts * (1.0f / DD);
  const float var = ts2 * (1.0f / DD) - mu * mu;
  const float inv = rsqrtf(var + 1e-5f);
  const float4 gv = ((const float4*)g)[t];
  const float4 bv = ((const float4*)bta)[t];
  bf16x4 o;
  o[0] = (__bf16)((x.x - mu) * inv * gv.x + bv.x);
  o[1] = (__bf16)((x.y - mu) * inv * gv.y + bv.y);
  o[2] = (__bf16)((x.z - mu) * inv * gv.z + bv.z);
  o[3] = (__bf16)((x.w - mu) * inv * gv.w + bv.w);
  *(bf16x4*)(out + (size_t)row * DD + t * 4) = o;
}

extern "C" void kernel_launch(void* const* d_in, const int* in_sizes, int n_in,
                              void* d_out, int out_size, void* d_ws, size_t ws_size,
                              hipStream_t stream) {
  (void)in_sizes; (void)n_in; (void)out_size; (void)ws_size;
  const int*   x    = (const int*)d_in[0];
  const float* emb  = (const float*)d_in[1];
  const float* Wq   = (const float*)d_in[2];
  const float* Wk   = (const float*)d_in[3];
  const float* Wv   = (const float*)d_in[4];
  const float* Wo   = (const float*)d_in[5];
  const float* ln_g = (const float*)d_in[6];
  const float* ln_b = (const float*)d_in[7];
  const float* outW = (const float*)d_in[8];
  const float* outb = (const float*)d_in[9];
  float* out = (float*)d_out;

  char* ws = (char*)d_ws;
  float*  ctx_f32 = (float*) (ws + 0);            // 33,554,432
  bf16_t* ctx_bf  = (bf16_t*)(ws + 33554432ull);  // 16,777,216
  float*  qkv     = (float*) (ws + 50331648ull);  // 41,943,040 (reused as h f32)
  bf16_t* attn_bf = (bf16_t*)(ws + 92274688ull);  // 16,777,216 (reused as h bf16)
  float*  Gbuf    = (float*) (ws + 109051904ull); //  2,097,152
  float*  KSbuf   = (float*) (ws + 111149056ull); //     16,384
  bf16_t* WqkvT   = (bf16_t*)(ws + 111165440ull); //  2,621,440
  bf16_t* WoT     = (bf16_t*)(ws + 113786880ull); //  2,097,152
  bf16_t* outWT   = (bf16_t*)(ws + 115884032ull); // 65,536,000  (end 181,420,032)
  float*  hbuf    = qkv;
  bf16_t* h_bf    = attn_bf;

  transpose_cvt<<<dim3(2, 16),   256, 0, stream>>>(Wq,   WqkvT,              DD, 128);
  transpose_cvt<<<dim3(2, 16),   256, 0, stream>>>(Wk,   WqkvT + 128 * DD,   DD, 128);
  transpose_cvt<<<dim3(16, 16),  256, 0, stream>>>(Wv,   WqkvT + 256 * DD,   DD, DD);
  transpose_cvt<<<dim3(16, 16),  256, 0, stream>>>(Wo,   WoT,                DD, DD);
  transpose_cvt<<<dim3(500, 16), 256, 0, stream>>>(outW, outWT,              DD, VV);

  ctx_kernel<<<BB * SS, 256, 0, stream>>>(x, emb, ctx_f32, ctx_bf);

  // QKV projection + fused phi on cols<256  (M=8192, N=1280, grid 5*32=160)
  gemm256_kernel<3><<<(QKVW / 256) * (BB * SS / 256), 512, 0, stream>>>(
      ctx_bf, WqkvT, qkv, nullptr, QKVW, DD, QKVW / 256);

  gstate_kernel<<<BB * NC * HH, 256, 0, stream>>>(qkv, Gbuf, KSbuf);
  attn_kernel<<<BB * NC * HH * 2, 256, 0, stream>>>(qkv, Gbuf, KSbuf, attn_bf);

  // out-proj + residual  (N=1024, grid 4*32=128)
  gemm256_kernel<2><<<(DD / 256) * (BB * SS / 256), 512, 0, stream>>>(
      attn_bf, WoT, hbuf, ctx_f32, DD, DD, DD / 256);

  ln_kernel<<<BB * SS, 256, 0, stream>>>(hbuf, ln_g, ln_b, h_bf);

  // logits + bias  (N=32000, grid 125*32=4000)
  gemm256_kernel<1><<<(VV / 256) * (BB * SS / 256), 512, 0, stream>>>(
      h_bf, outWT, out, outb, VV, DD, VV / 256);
}

// Round 6
// 1067.675 us; speedup vs baseline: 1.2233x; 1.0868x over previous
//
#include <hip/hip_runtime.h>
#include <hip/hip_bf16.h>

typedef __bf16 bf16_t;
typedef __bf16 bf16x4 __attribute__((ext_vector_type(4)));
typedef __bf16 bf16x8 __attribute__((ext_vector_type(8)));
typedef float f32x4 __attribute__((ext_vector_type(4)));

#define BB 2
#define SS 4096
#define DD 1024
#define VV 32000
#define HH 8
#define CC 256
#define NC 16
#define QKVW 1280   // q(128) | k(128) | v(1024)

#define GLD_LDS16(gp, lp) __builtin_amdgcn_global_load_lds( \
    (const __attribute__((address_space(1))) void*)(gp),    \
    (__attribute__((address_space(3))) void*)(lp), 16, 0, 0)

// ---------------- ctx: emb gather + 4-tap causal sum ----------------
__global__ __launch_bounds__(256) void ctx_kernel(
    const int* __restrict__ x, const float* __restrict__ emb,
    float* __restrict__ ctx, bf16_t* __restrict__ ctxb)
{
  const int row = blockIdx.x;            // b*SS + s
  const int b = row >> 12, s = row & (SS - 1);
  const int t = threadIdx.x;             // d = t*4
  float4 a = make_float4(0.f, 0.f, 0.f, 0.f);
  #pragma unroll
  for (int o = 0; o < 4; ++o) {
    if (s - o >= 0) {
      const int idx = x[b * SS + s - o];
      const float4 e = *(const float4*)(emb + (size_t)idx * DD + t * 4);
      a.x += e.x; a.y += e.y; a.z += e.z; a.w += e.w;
    }
  }
  *(float4*)(ctx + (size_t)row * DD + t * 4) = a;
  bf16x4 bv;
  bv[0] = (__bf16)a.x; bv[1] = (__bf16)a.y; bv[2] = (__bf16)a.z; bv[3] = (__bf16)a.w;
  *(bf16x4*)(ctxb + (size_t)row * DD + t * 4) = bv;
}

// ---------------- transpose + f32->bf16: dst[c][r] = src[r][c] ----------------
__global__ __launch_bounds__(256) void transpose_cvt(
    const float* __restrict__ src, bf16_t* __restrict__ dst,
    int srcRows, int srcCols)
{
  __shared__ __align__(16) float tile[64][65];
  const int c0 = blockIdx.x * 64, r0 = blockIdx.y * 64;
  const int tc = threadIdx.x & 63, tq = threadIdx.x >> 6;
  #pragma unroll
  for (int k = 0; k < 16; ++k) {
    const int r = k * 4 + tq;
    tile[r][tc] = src[(size_t)(r0 + r) * srcCols + c0 + tc];
  }
  __syncthreads();
  #pragma unroll
  for (int k = 0; k < 16; ++k) {
    const int cO = k * 4 + tq;
    dst[(size_t)(c0 + cO) * srcRows + r0 + tc] = (__bf16)tile[tc][cO];
  }
}

// ================= 256x256 tile, BK=64, 8-wave, 4-phase pipelined GEMM =======
// C[M,N] = A[M,K] @ BT[N,K]^T.  EPI: 0=none, 1=+bias[col], 2=+res, 3=phi(col<256)
// R5: memory-supply fix (R4 FETCH=1.08GB vs 81MB compulsory => B re-fetched
// ~16x from HBM; L3 thrashed by C-stream).
//  (1) 2-D slab swizzle: XCD owns a 4-row A-slab (2MB, L2-resident); its 32
//      concurrent CUs form an 8bx x 4by cluster so B-tiles are L2-shared x4.
//  (2) nontemporal C stores: keep the 1GB logit stream from evicting B.
// Staging cadence (quarters, 2 loads/thread each), tile k phases q0..q3:
//   q0: Aq13[k+1] -> buf^1   q1: Bnh1[k+1] -> buf^1
//   q2: Aq02[k+2] -> buf     q3: Bnh0[k+2] -> buf, then vmcnt(4)
// Reads: q0: A_MH0(8) + B n0,n1(4); q1: B n2,n3(4); q2: A_MH1(8); q3: none.

#define STG_AQ02(SRC, RB, LDSB, KT) do {                                      \
  const size_t _k = (size_t)(KT) * 64;                                        \
  GLD_LDS16((SRC) + (size_t)((RB) + (t >> 3)) * K + _k + cg8,                 \
            (LDSB) + (size_t)(t & ~63) * 8);                                  \
  GLD_LDS16((SRC) + (size_t)((RB) + 128 + (t >> 3)) * K + _k + cg8,          \
            (LDSB) + 8192 + (size_t)(t & ~63) * 8);                           \
} while (0)

#define STG_AQ13(SRC, RB, LDSB, KT) do {                                      \
  const size_t _k = (size_t)(KT) * 64;                                        \
  GLD_LDS16((SRC) + (size_t)((RB) + 64 + (t >> 3)) * K + _k + cg8,           \
            (LDSB) + 4096 + (size_t)(t & ~63) * 8);                           \
  GLD_LDS16((SRC) + (size_t)((RB) + 192 + (t >> 3)) * K + _k + cg8,          \
            (LDSB) + 12288 + (size_t)(t & ~63) * 8);                          \
} while (0)

#define STG_BNH0(SRC, RB, LDSB, KT) do {                                      \
  const size_t _k = (size_t)(KT) * 64;                                        \
  const int _r = (t >> 3) + ((t >> 8) << 5);                                  \
  const int _u = ((t & ~63) + ((t >> 8) << 8)) * 8;                           \
  GLD_LDS16((SRC) + (size_t)((RB) + _r) * K + _k + cg8, (LDSB) + _u);        \
  GLD_LDS16((SRC) + (size_t)((RB) + 128 + _r) * K + _k + cg8,                \
            (LDSB) + 8192 + _u);                                              \
} while (0)

#define STG_BNH1(SRC, RB, LDSB, KT) do {                                      \
  const size_t _k = (size_t)(KT) * 64;                                        \
  const int _r = (t >> 3) + ((t >> 8) << 5);                                  \
  const int _u = ((t & ~63) + ((t >> 8) << 8)) * 8;                           \
  GLD_LDS16((SRC) + (size_t)((RB) + 32 + _r) * K + _k + cg8,                 \
            (LDSB) + 2048 + _u);                                              \
  GLD_LDS16((SRC) + (size_t)((RB) + 160 + _r) * K + _k + cg8,                \
            (LDSB) + 10240 + _u);                                             \
} while (0)

#define READ_A(MH) do {                                                       \
  _Pragma("unroll") for (int mi = 0; mi < 4; ++mi) {                          \
    const bf16_t* ap = Ac + (size_t)(wr * 128 + (MH) * 64 + mi * 16 + lr) * 64; \
    af[mi][0] = *(const bf16x8*)(ap + c0);                                    \
    af[mi][1] = *(const bf16x8*)(ap + c1);                                    \
  } } while (0)

#define READ_B2(NB) do {                                                      \
  _Pragma("unroll") for (int nj = 0; nj < 2; ++nj) {                          \
    const bf16_t* bp = Bc + (size_t)(wc * 64 + ((NB) + nj) * 16 + lr) * 64;   \
    bfr[(NB) + nj][0] = *(const bf16x8*)(bp + c0);                            \
    bfr[(NB) + nj][1] = *(const bf16x8*)(bp + c1);                            \
  } } while (0)

#define MFMA8(MH, NB) do {                                                    \
  _Pragma("unroll") for (int mi = 0; mi < 4; ++mi)                            \
    _Pragma("unroll") for (int nj = 0; nj < 2; ++nj) {                        \
      acc[(MH)*4+mi][(NB)+nj] = __builtin_amdgcn_mfma_f32_16x16x32_bf16(      \
          af[mi][0], bfr[(NB)+nj][0], acc[(MH)*4+mi][(NB)+nj], 0, 0, 0);      \
      acc[(MH)*4+mi][(NB)+nj] = __builtin_amdgcn_mfma_f32_16x16x32_bf16(      \
          af[mi][1], bfr[(NB)+nj][1], acc[(MH)*4+mi][(NB)+nj], 0, 0, 0);      \
    } } while (0)

#define PH_SYNC() do {                                                        \
  __builtin_amdgcn_s_barrier();                                               \
  asm volatile("s_waitcnt lgkmcnt(0)" ::: "memory");                          \
  __builtin_amdgcn_sched_barrier(0);                                          \
} while (0)

template<int EPI>
__global__ __launch_bounds__(512, 2) void gemm256_kernel(
    const bf16_t* __restrict__ A, const bf16_t* __restrict__ BT,
    float* __restrict__ C, const float* __restrict__ extra,
    int N, int K, int GX)
{
  __shared__ __align__(16) bf16_t AsBuf[2][256 * 64];
  __shared__ __align__(16) bf16_t BsBuf[2][256 * 64];
  // 2-D slab swizzle: GY = nwg/GX rows of blocks, SLAB = GY/8 rows per XCD.
  // xcd = bid&7 (assumes round-robin dispatch; perf-only heuristic).
  const int nwg = gridDim.x;
  const int bid = blockIdx.x;
  const int GYl = nwg / GX;
  const int SLAB = GYl >> 3;
  const int xcd = bid & 7, i = bid >> 3;
  const int by = xcd * SLAB + (i % SLAB);
  const int bx = i / SLAB;
  const int n0 = bx * 256, m0 = by * 256;
  const int t = threadIdx.x;
  const int lane = t & 63, w = t >> 6;
  const int wr = w >> 2, wc = w & 3;
  const int lr = lane & 15, lq = lane >> 4;
  const int rx = lr & 7;
  const int c0 = ((0 + lq) ^ rx) * 8;                  // ks=0 read col (elems)
  const int c1 = ((4 + lq) ^ rx) * 8;                  // ks=1
  const int cg8 = (((t & 7) ^ ((t >> 3) & 7))) * 8;    // stage pre-swizzled col
  const int NT = K >> 6;                               // K-tiles
  f32x4 acc[8][4] = {};

  // prologue: cadence-consistent issue of tiles 0,1 (12 loads), vmcnt(4)
  STG_AQ02(A,  m0, AsBuf[0], 0);
  STG_BNH0(BT, n0, BsBuf[0], 0);
  STG_AQ13(A,  m0, AsBuf[0], 0);
  STG_BNH1(BT, n0, BsBuf[0], 0);
  STG_AQ02(A,  m0, AsBuf[1], 1);
  STG_BNH0(BT, n0, BsBuf[1], 1);
  asm volatile("s_waitcnt vmcnt(4)" ::: "memory");
  __builtin_amdgcn_s_barrier();

  for (int k = 0; k < NT; ++k) {
    const bf16_t* Ac = AsBuf[k & 1];
    const bf16_t* Bc = BsBuf[k & 1];
    bf16_t* An = AsBuf[(k + 1) & 1];
    bf16_t* Bn = BsBuf[(k + 1) & 1];
    bf16_t* Ak = AsBuf[k & 1];
    bf16_t* Bk = BsBuf[k & 1];
    const bool s1 = (k + 1 < NT), s2 = (k + 2 < NT);
    bf16x8 af[4][2], bfr[4][2];
    // ---- q0: read A_MH0 + B n0,n1; stage Aq13[k+1]
    READ_A(0); READ_B2(0);
    if (s1) STG_AQ13(A, m0, An, k + 1);
    PH_SYNC();
    __builtin_amdgcn_s_setprio(1);
    MFMA8(0, 0);
    __builtin_amdgcn_s_setprio(0);
    __builtin_amdgcn_s_barrier();
    // ---- q1: read B n2,n3; stage Bnh1[k+1]
    READ_B2(2);
    if (s1) STG_BNH1(BT, n0, Bn, k + 1);
    PH_SYNC();
    __builtin_amdgcn_s_setprio(1);
    MFMA8(0, 2);
    __builtin_amdgcn_s_setprio(0);
    __builtin_amdgcn_s_barrier();
    // ---- q2: read A_MH1; stage Aq02[k+2]
    READ_A(1);
    if (s2) STG_AQ02(A, m0, Ak, k + 2);
    PH_SYNC();
    __builtin_amdgcn_s_setprio(1);
    MFMA8(1, 0);
    __builtin_amdgcn_s_setprio(0);
    __builtin_amdgcn_s_barrier();
    // ---- q3: register-only MFMA; stage Bnh0[k+2]; counted vmcnt
    if (s2) STG_BNH0(BT, n0, Bk, k + 2);
    __builtin_amdgcn_s_setprio(1);
    MFMA8(1, 2);
    __builtin_amdgcn_s_setprio(0);
    if (k < NT - 2) { asm volatile("s_waitcnt vmcnt(4)" ::: "memory"); }
    else if (k == NT - 2) { asm volatile("s_waitcnt vmcnt(0)" ::: "memory"); }
    __builtin_amdgcn_s_barrier();
  }

  // epilogue: C/D layout col=lane&15, row=(lane>>4)*4+reg  [m89-verified]
  // nontemporal stores: don't let the C stream evict B from L2/L3.
  #pragma unroll
  for (int mi = 0; mi < 8; ++mi) {
    #pragma unroll
    for (int r = 0; r < 4; ++r) {
      const int row = m0 + wr * 128 + mi * 16 + lq * 4 + r;
      #pragma unroll
      for (int ni = 0; ni < 4; ++ni) {
        const int col = n0 + wc * 64 + ni * 16 + lr;
        float v = acc[mi][ni][r];
        if (EPI == 1) v += extra[col];
        if (EPI == 2) v += extra[(size_t)row * N + col];
        if (EPI == 3) { if (col < 256) v = v > 0.f ? v + 1.f : __expf(v); }
        __builtin_nontemporal_store(v, &C[(size_t)row * N + col]);
      }
    }
  }
}

// ---------------- per-chunk G = K^T V and ksum ----------------
__global__ __launch_bounds__(256) void gstate_kernel(
    const float* __restrict__ qkv, float* __restrict__ G, float* __restrict__ KS)
{
  const int g = blockIdx.x;                    // b*128 + c*8 + h
  const int h = g & 7, c = (g >> 3) & 15, b = g >> 7;
  const int t = threadIdx.x;
  const int i = t >> 4, dg = t & 15;           // k-index, 8-col group
  const int srcbase = b * SS + c * CC;
  __shared__ __align__(16) float k_lds[64][16];
  __shared__ __align__(16) float v_lds[64][128];
  float acc[8] = {0,0,0,0,0,0,0,0};
  float ks = 0.f;
  for (int st = 0; st < 4; ++st) {
    __syncthreads();
    { const int sl = t >> 2, i0 = (t & 3) * 4;
      *(float4*)&k_lds[sl][i0] =
        *(const float4*)(qkv + (size_t)(srcbase + st * 64 + sl) * QKVW + 128 + h * 16 + i0); }
    #pragma unroll
    for (int vv = 0; vv < 8; ++vv) {
      const int sl = (t >> 5) + vv * 8, col = (t & 31) * 4;
      *(float4*)&v_lds[sl][col] =
        *(const float4*)(qkv + (size_t)(srcbase + st * 64 + sl) * QKVW + 256 + h * 128 + col);
    }
    __syncthreads();
    for (int sl = 0; sl < 64; ++sl) {
      const float kv = k_lds[sl][i];
      if (dg == 0) ks += kv;
      const float4 va = *(const float4*)&v_lds[sl][dg * 8];
      const float4 vb = *(const float4*)&v_lds[sl][dg * 8 + 4];
      acc[0] = fmaf(kv, va.x, acc[0]); acc[1] = fmaf(kv, va.y, acc[1]);
      acc[2] = fmaf(kv, va.z, acc[2]); acc[3] = fmaf(kv, va.w, acc[3]);
      acc[4] = fmaf(kv, vb.x, acc[4]); acc[5] = fmaf(kv, vb.y, acc[5]);
      acc[6] = fmaf(kv, vb.z, acc[6]); acc[7] = fmaf(kv, vb.w, acc[7]);
    }
  }
  float* gp = G + ((size_t)(b * NC + c) * HH + h) * 2048 + i * 128 + dg * 8;
  *(float4*)gp       = make_float4(acc[0], acc[1], acc[2], acc[3]);
  *(float4*)(gp + 4) = make_float4(acc[4], acc[5], acc[6], acc[7]);
  if (dg == 0) KS[((size_t)(b * NC + c) * HH + h) * 16 + i] = ks;
}

// ---------------- attention: intra (masked) + bypass (prev chunk) + state ----------------
__global__ __launch_bounds__(256) void attn_kernel(
    const float* __restrict__ qkv, const float* __restrict__ Gb,
    const float* __restrict__ KS, bf16_t* __restrict__ outp)
{
  const int bid = blockIdx.x;                   // 512 = b*256 + c*16 + h*2 + dh
  const int dh = bid & 1, h = (bid >> 1) & 7, c = (bid >> 4) & 15, b = bid >> 8;
  const int t = threadIdx.x;
  const int cg = t & 3, rg = t >> 2;            // 16-col group, 4-row group
  const int rowbase = b * SS + c * CC;

  __shared__ __align__(16) float k_lds[64][16];
  __shared__ __align__(16) float v_lds[64][64];
  __shared__ __align__(16) float s_lds[16 * 64];
  __shared__ float z_lds[16];

  float q[4][16];
  #pragma unroll
  for (int rr = 0; rr < 4; ++rr) {
    const float* qp = qkv + (size_t)(rowbase + rg * 4 + rr) * QKVW + h * 16;
    #pragma unroll
    for (int i4 = 0; i4 < 4; ++i4) {
      const float4 qv = *(const float4*)(qp + i4 * 4);
      q[rr][i4*4+0] = qv.x; q[rr][i4*4+1] = qv.y; q[rr][i4*4+2] = qv.z; q[rr][i4*4+3] = qv.w;
    }
  }
  float acc[4][16] = {};
  float den[4] = {0.f, 0.f, 0.f, 0.f};

  for (int ph = 0; ph < 2; ++ph) {
    const int cc = c - ph;                       // ph0: current chunk (masked); ph1: prev chunk
    if (cc < 0) break;
    const int srcbase = b * SS + cc * CC;
    const bool masked = (ph == 0);
    for (int st = 0; st < 4; ++st) {
      __syncthreads();
      { const int sl = t >> 2, i0 = (t & 3) * 4;
        *(float4*)&k_lds[sl][i0] =
          *(const float4*)(qkv + (size_t)(srcbase + st * 64 + sl) * QKVW + 128 + h * 16 + i0); }
      #pragma unroll
      for (int vv = 0; vv < 4; ++vv) {
        const int sl = (t >> 4) + vv * 16, col = (t & 15) * 4;
        *(float4*)&v_lds[sl][col] =
          *(const float4*)(qkv + (size_t)(srcbase + st * 64 + sl) * QKVW + 256 + h * 128 + dh * 64 + col);
      }
      __syncthreads();
      for (int sl = 0; sl < 64; ++sl) {
        float kv[16], vvv[16];
        #pragma unroll
        for (int i4 = 0; i4 < 4; ++i4) {
          const float4 kf = *(const float4*)&k_lds[sl][i4 * 4];
          kv[i4*4+0] = kf.x; kv[i4*4+1] = kf.y; kv[i4*4+2] = kf.z; kv[i4*4+3] = kf.w;
          const float4 vf = *(const float4*)&v_lds[sl][cg * 16 + i4 * 4];
          vvv[i4*4+0] = vf.x; vvv[i4*4+1] = vf.y; vvv[i4*4+2] = vf.z; vvv[i4*4+3] = vf.w;
        }
        const int sidx = st * 64 + sl;
        #pragma unroll
        for (int rr = 0; rr < 4; ++rr) {
          float a = 0.f;
          #pragma unroll
          for (int i = 0; i < 16; ++i) a = fmaf(q[rr][i], kv[i], a);
          if (masked && sidx > rg * 4 + rr) a = 0.f;
          den[rr] += a;                          // intra: q.kcum ; bypass: q.bksum
          #pragma unroll
          for (int e = 0; e < 16; ++e) acc[rr][e] = fmaf(a, vvv[e], acc[rr][e]);
        }
      }
    }
  }

  if (c >= 2) {                                  // long-range state: sum_{j<=c-2} G_j
    float sa0 = 0.f, sa1 = 0.f, sa2 = 0.f, sa3 = 0.f;
    const int si = t >> 4, sc = (t & 15) * 4;
    for (int j = 0; j + 2 <= c; ++j) {
      const float4 gv = *(const float4*)(Gb + ((size_t)(b * NC + j) * HH + h) * 2048
                                            + si * 128 + dh * 64 + sc);
      sa0 += gv.x; sa1 += gv.y; sa2 += gv.z; sa3 += gv.w;
    }
    if (t < 16) {
      float z = 0.f;
      for (int j = 0; j + 2 <= c; ++j) z += KS[((size_t)(b * NC + j) * HH + h) * 16 + t];
      z_lds[t] = z;
    }
    *(float4*)&s_lds[si * 64 + sc] = make_float4(sa0, sa1, sa2, sa3);
    __syncthreads();
    #pragma unroll
    for (int i = 0; i < 16; ++i) {
      float sv[16];
      #pragma unroll
      for (int e4 = 0; e4 < 4; ++e4) {
        const float4 f = *(const float4*)&s_lds[i * 64 + cg * 16 + e4 * 4];
        sv[e4*4+0] = f.x; sv[e4*4+1] = f.y; sv[e4*4+2] = f.z; sv[e4*4+3] = f.w;
      }
      const float zi = z_lds[i];
      #pragma unroll
      for (int rr = 0; rr < 4; ++rr) {
        const float qv = q[rr][i];
        den[rr] = fmaf(qv, zi, den[rr]);
        #pragma unroll
        for (int e = 0; e < 16; ++e) acc[rr][e] = fmaf(qv, sv[e], acc[rr][e]);
      }
    }
  }

  const size_t obase = (size_t)rowbase * DD + h * 128 + dh * 64 + cg * 16;
  #pragma unroll
  for (int rr = 0; rr < 4; ++rr) {
    const float inv = 1.0f / (den[rr] + 1e-6f);
    bf16_t* op = outp + obase + (size_t)(rg * 4 + rr) * DD;
    #pragma unroll
    for (int e4 = 0; e4 < 4; ++e4) {
      bf16x4 bv;
      bv[0] = (__bf16)(acc[rr][e4*4+0] * inv); bv[1] = (__bf16)(acc[rr][e4*4+1] * inv);
      bv[2] = (__bf16)(acc[rr][e4*4+2] * inv); bv[3] = (__bf16)(acc[rr][e4*4+3] * inv);
      *(bf16x4*)(op + e4 * 4) = bv;
    }
  }
}

// ---------------- LayerNorm (eps 1e-5) -> bf16 ----------------
__global__ __launch_bounds__(256) void ln_kernel(
    const float* __restrict__ hbuf, const float* __restrict__ g,
    const float* __restrict__ bta, bf16_t* __restrict__ out)
{
  const int row = blockIdx.x;
  const int t = threadIdx.x;
  const float4 x = ((const float4*)(hbuf + (size_t)row * DD))[t];
  float s  = x.x + x.y + x.z + x.w;
  float s2 = x.x*x.x + x.y*x.y + x.z*x.z + x.w*x.w;
  #pragma unroll
  for (int off = 32; off > 0; off >>= 1) {
    s  += __shfl_down(s,  off, 64);
    s2 += __shfl_down(s2, off, 64);
  }
  __shared__ float ws[8];
  if ((t & 63) == 0) { ws[(t >> 6) * 2] = s; ws[(t >> 6) * 2 + 1] = s2; }
  __syncthreads();
  const float ts  = ws[0] + ws[2] + ws[4] + ws[6];
  const float ts2 = ws[1] + ws[3] + ws[5] + ws[7];
  const float mu  = ts * (1.0f / DD);
  const float var = ts2 * (1.0f / DD) - mu * mu;
  const float inv = rsqrtf(var + 1e-5f);
  const float4 gv = ((const float4*)g)[t];
  const float4 bv = ((const float4*)bta)[t];
  bf16x4 o;
  o[0] = (__bf16)((x.x - mu) * inv * gv.x + bv.x);
  o[1] = (__bf16)((x.y - mu) * inv * gv.y + bv.y);
  o[2] = (__bf16)((x.z - mu) * inv * gv.z + bv.z);
  o[3] = (__bf16)((x.w - mu) * inv * gv.w + bv.w);
  *(bf16x4*)(out + (size_t)row * DD + t * 4) = o;
}

extern "C" void kernel_launch(void* const* d_in, const int* in_sizes, int n_in,
                              void* d_out, int out_size, void* d_ws, size_t ws_size,
                              hipStream_t stream) {
  (void)in_sizes; (void)n_in; (void)out_size; (void)ws_size;
  const int*   x    = (const int*)d_in[0];
  const float* emb  = (const float*)d_in[1];
  const float* Wq   = (const float*)d_in[2];
  const float* Wk   = (const float*)d_in[3];
  const float* Wv   = (const float*)d_in[4];
  const float* Wo   = (const float*)d_in[5];
  const float* ln_g = (const float*)d_in[6];
  const float* ln_b = (const float*)d_in[7];
  const float* outW = (const float*)d_in[8];
  const float* outb = (const float*)d_in[9];
  float* out = (float*)d_out;

  char* ws = (char*)d_ws;
  float*  ctx_f32 = (float*) (ws + 0);            // 33,554,432
  bf16_t* ctx_bf  = (bf16_t*)(ws + 33554432ull);  // 16,777,216
  float*  qkv     = (float*) (ws + 50331648ull);  // 41,943,040 (reused as h f32)
  bf16_t* attn_bf = (bf16_t*)(ws + 92274688ull);  // 16,777,216 (reused as h bf16)
  float*  Gbuf    = (float*) (ws + 109051904ull); //  2,097,152
  float*  KSbuf   = (float*) (ws + 111149056ull); //     16,384
  bf16_t* WqkvT   = (bf16_t*)(ws + 111165440ull); //  2,621,440
  bf16_t* WoT     = (bf16_t*)(ws + 113786880ull); //  2,097,152
  bf16_t* outWT   = (bf16_t*)(ws + 115884032ull); // 65,536,000  (end 181,420,032)
  float*  hbuf    = qkv;
  bf16_t* h_bf    = attn_bf;

  transpose_cvt<<<dim3(2, 16),   256, 0, stream>>>(Wq,   WqkvT,              DD, 128);
  transpose_cvt<<<dim3(2, 16),   256, 0, stream>>>(Wk,   WqkvT + 128 * DD,   DD, 128);
  transpose_cvt<<<dim3(16, 16),  256, 0, stream>>>(Wv,   WqkvT + 256 * DD,   DD, DD);
  transpose_cvt<<<dim3(16, 16),  256, 0, stream>>>(Wo,   WoT,                DD, DD);
  transpose_cvt<<<dim3(500, 16), 256, 0, stream>>>(outW, outWT,              DD, VV);

  ctx_kernel<<<BB * SS, 256, 0, stream>>>(x, emb, ctx_f32, ctx_bf);

  // QKV projection + fused phi on cols<256  (M=8192, N=1280, grid 5*32=160)
  gemm256_kernel<3><<<(QKVW / 256) * (BB * SS / 256), 512, 0, stream>>>(
      ctx_bf, WqkvT, qkv, nullptr, QKVW, DD, QKVW / 256);

  gstate_kernel<<<BB * NC * HH, 256, 0, stream>>>(qkv, Gbuf, KSbuf);
  attn_kernel<<<BB * NC * HH * 2, 256, 0, stream>>>(qkv, Gbuf, KSbuf, attn_bf);

  // out-proj + residual  (N=1024, grid 4*32=128)
  gemm256_kernel<2><<<(DD / 256) * (BB * SS / 256), 512, 0, stream>>>(
      attn_bf, WoT, hbuf, ctx_f32, DD, DD, DD / 256);

  ln_kernel<<<BB * SS, 256, 0, stream>>>(hbuf, ln_g, ln_b, h_bf);

  // logits + bias  (N=32000, grid 125*32=4000)
  gemm256_kernel<1><<<(VV / 256) * (BB * SS / 256), 512, 0, stream>>>(
      h_bf, outWT, out, outb, VV, DD, VV / 256);
}